// Round 20
// baseline (110.192 us; speedup 1.0000x reference)
//
#include <hip/hip_runtime.h>
#include <math.h>

#define N_PTS 4096
#define BATCH 4
#define JS 8                  // j-split factor
#define JCH (N_PTS / JS)      // 512 points per j-chunk

typedef short bf16x8 __attribute__((ext_vector_type(8)));
typedef short bf16x4 __attribute__((ext_vector_type(4)));
typedef float f32x4 __attribute__((ext_vector_type(4)));
typedef _Float16 f16x8 __attribute__((ext_vector_type(8)));

__device__ inline short f2h(float f) {
    _Float16 h = (_Float16)f;
    return __builtin_bit_cast(short, h);
}

__device__ inline void gload_lds16(const void* g, void* l) {
    __builtin_amdgcn_global_load_lds(
        (const __attribute__((address_space(1))) unsigned int*)g,
        (__attribute__((address_space(3))) unsigned int*)l, 16, 0, 0);
}

// ---------------------------------------------------------------------------
// Weight-conversion args (6 layers)
// ---------------------------------------------------------------------------
struct WcArgs {
    const float* W[6];
    short* O[6];
    int M[6], K[6], Kp[6];
    int start[7];
};

// ===========================================================================
// Device bodies
// ===========================================================================

// wconv body -----------------------------------------------------------------
__device__ __forceinline__ void wconv_body(const WcArgs& a, int bx, int tid)
{
    int id = bx * 256 + tid;
    if (id >= a.start[6]) return;
    int l = 0;
    #pragma unroll
    for (int q = 1; q < 6; ++q) if (id >= a.start[q]) l = q;
    int local = id - a.start[l];
    int kp = a.Kp[l];
    int mrow = local / kp, k = local - mrow * kp;
    float v = (mrow < a.M[l] && k < a.K[l]) ? a.W[l][(size_t)mrow * a.K[l] + k] : 0.f;
    a.O[l][local] = f2h(v);
}

// radius body (triangular; per-block partial max, no atomics) ----------------
__device__ __forceinline__ void radius_body(
    const float* __restrict__ xyz, float* __restrict__ pmax,
    int ci, int js, int b, int tid, char* smem)
{
    if (ci >= 8 * js + 8) return;              // uniform triangular exit
    float4* sj = (float4*)smem;                // JCH*16 = 8 KB
    float* wred = (float*)(smem + JCH * 16);
    const float* xb = xyz + (size_t)b * N_PTS * 3;
    const int j0 = js * JCH;
    for (int idx = tid; idx < JCH; idx += 256) {
        int j = j0 + idx;
        float x = xb[j*3+0], y = xb[j*3+1], z = xb[j*3+2];
        sj[idx] = make_float4(x, y, z, fmaf(x, x, fmaf(y, y, z * z)));
    }
    __syncthreads();
    const int il = tid & 63;
    const int jq = tid >> 6;
    const int i = ci * 64 + il;
    const float xi = xb[i*3+0], yi = xb[i*3+1], zi = xb[i*3+2];
    const float x2i = fmaf(xi, xi, fmaf(yi, yi, zi * zi));
    float m = 0.f;
    const int jb = jq * (JCH / 4);
    #pragma unroll 4
    for (int j = jb; j < jb + JCH / 4; ++j) {
        float4 p = sj[j];
        float dot = fmaf(xi, p.x, fmaf(yi, p.y, zi * p.z));
        float d2 = fmaf(-2.f, dot, x2i + p.w);
        m = fmaxf(m, d2);
    }
    for (int off = 32; off >= 1; off >>= 1) m = fmaxf(m, __shfl_down(m, off));
    if ((tid & 63) == 0) wred[tid >> 6] = m;
    __syncthreads();
    if (tid == 0) {
        float mm = fmaxf(fmaxf(wred[0], wred[1]), fmaxf(wred[2], wred[3]));
        pmax[((size_t)b * JS + js) * 64 + ci] = mm;
    }
}

// transpose body, 64-COLUMN tiles (r20): [128][64] f32 tile, 8 float4 loads
// in flight per thread. Element (c,n): quad qs = (n>>2) ^ ((c>>3)&7),
// offset n&3 (involution, same on write and read). Read banks 32 / 2-way.
__device__ __forceinline__ void transpose64_body(
    const float* __restrict__ h2, const float* __restrict__ h1,
    short* __restrict__ t_h2, short* __restrict__ zinT,
    int x, int y, int b, int tid, char* smem)
{
    float (*tile)[64] = (float(*)[64])smem;    // 32 KB
    const int n0 = x * 64;
    const float* src = (y < 8)
        ? h2 + ((size_t)b * 1024 + y * 128) * N_PTS
        : h1 + (size_t)b * 128 * N_PTS;
    // load: 128 rows x 16 float4 = 2048 quads, 8 iters (8 loads in flight)
    #pragma unroll
    for (int it = 0; it < 8; ++it) {
        int idx = it * 256 + tid;
        int c = idx >> 4, q = idx & 15;
        int qs = q ^ ((c >> 3) & 7);
        *(float4*)&tile[c][qs * 4] = *(const float4*)&src[(size_t)c * N_PTS + n0 + q * 4];
    }
    __syncthreads();
    // write: 64 n x 16 channel-groups(8) = 1024, 4 iters
    if (y < 8) {
        const int c0 = y * 128;
        #pragma unroll
        for (int it = 0; it < 4; ++it) {
            int idx = it * 256 + tid;
            int n = idx >> 4, cg = idx & 15;
            bf16x8 v;
            #pragma unroll
            for (int j = 0; j < 8; ++j) {
                int c = cg * 8 + j;
                int col = (((n >> 2) ^ ((c >> 3) & 7)) << 2) | (n & 3);
                v[j] = f2h(tile[c][col]);
            }
            *(bf16x8*)&t_h2[((size_t)b * N_PTS + n0 + n) * 1024 + c0 + cg * 8] = v;
        }
    } else {
        #pragma unroll
        for (int it = 0; it < 4; ++it) {
            int idx = it * 256 + tid;
            int n = idx >> 4, cg = idx & 15;
            bf16x8 v;
            #pragma unroll
            for (int j = 0; j < 8; ++j) {
                int c = cg * 8 + j;
                int col = (((n >> 2) ^ ((c >> 3) & 7)) << 2) | (n & 3);
                v[j] = f2h(tile[c][col]);
            }
            *(bf16x8*)&zinT[((size_t)b * N_PTS + n0 + n) * 192 + cg * 8] = v;
        }
        for (int idx = tid; idx < 64 * 7; idx += 256) {
            int n = idx / 7, cq = 164 + (idx % 7) * 4;
            bf16x4 z = {0, 0, 0, 0};
            *(bf16x4*)&zinT[((size_t)b * N_PTS + n0 + n) * 192 + cq] = z;
        }
    }
}

// eigen accumulate body (MFMA mask GEMM; r2 from exact pmax reduce) ----------
__device__ __forceinline__ void accum_body(
    const float* __restrict__ xyz, const float* __restrict__ pmax,
    float* __restrict__ pbuf, int ci, int js, int b, int tid, char* smem)
{
    float4* sj4 = (float4*)smem;                               // 8 KB
    _Float16 (*Ft)[JCH + 8] = (_Float16(*)[JCH + 8])(smem + 8192);  // 16.25 KB
    float* redbuf = (float*)(smem + 8192 + 16 * (JCH + 8) * 2);

    const int lane = tid & 63, wave = tid >> 6;

    float mval = 0.f;
    for (int e = tid; e < 512; e += 256) {
        int js2 = e >> 6, ci2 = e & 63;
        float v = (ci2 < 8 * js2 + 8) ? pmax[((size_t)b * JS + js2) * 64 + ci2] : 0.f;
        mval = fmaxf(mval, v);
    }
    for (int off = 32; off >= 1; off >>= 1) mval = fmaxf(mval, __shfl_down(mval, off));
    if (lane == 0) redbuf[wave] = mval;

    const float* xb = xyz + (size_t)b * N_PTS * 3;
    const int j0g = js * JCH;
    for (int idx = tid; idx < JCH; idx += 256) {
        int j = j0g + idx;
        float x = xb[j*3+0], y = xb[j*3+1], z = xb[j*3+2];
        sj4[idx] = make_float4(x, y, z, fmaf(x, x, fmaf(y, y, z * z)));
        Ft[0][idx] = (_Float16)1.f;
        Ft[1][idx] = (_Float16)x;
        Ft[2][idx] = (_Float16)y;
        Ft[3][idx] = (_Float16)z;
        Ft[4][idx] = (_Float16)(x * x);
        Ft[5][idx] = (_Float16)(x * y);
        Ft[6][idx] = (_Float16)(x * z);
        Ft[7][idx] = (_Float16)(y * y);
        Ft[8][idx] = (_Float16)(y * z);
        Ft[9][idx] = (_Float16)(z * z);
        Ft[10][idx] = (_Float16)0.f; Ft[11][idx] = (_Float16)0.f;
        Ft[12][idx] = (_Float16)0.f; Ft[13][idx] = (_Float16)0.f;
        Ft[14][idx] = (_Float16)0.f; Ft[15][idx] = (_Float16)0.f;
    }
    __syncthreads();
    const float mm = fmaxf(fmaxf(redbuf[0], redbuf[1]), fmaxf(redbuf[2], redbuf[3]));
    const float r2 = 0.01f * mm;

    const int r = lane & 15, g = lane >> 4;
    const int i_wf = ci * 64 + wave * 16 + r;
    const float xi = xb[i_wf*3+0], yi = xb[i_wf*3+1], zi = xb[i_wf*3+2];
    const float x2i = fmaf(xi, xi, fmaf(yi, yi, zi * zi));

    f32x4 acc = (f32x4){0.f, 0.f, 0.f, 0.f};
    #pragma unroll 4
    for (int t = 0; t < JCH / 32; ++t) {
        const int jb = t * 32 + g * 8;
        f16x8 wfv;
        #pragma unroll
        for (int s = 0; s < 8; ++s) {
            float4 p = sj4[jb + s];
            float dot = fmaf(xi, p.x, fmaf(yi, p.y, zi * p.z));
            float d2 = fmaf(-2.f, dot, x2i + p.w);
            wfv[s] = (d2 < r2) ? (_Float16)1.f : (_Float16)0.f;
        }
        f16x8 fv = *(const f16x8*)&Ft[r][jb];
        acc = __builtin_amdgcn_mfma_f32_16x16x32_f16(wfv, fv, acc, 0, 0, 0);
    }

    const int i_out = ci * 64 + wave * 16 + g * 4;
    float* dst = pbuf + ((size_t)(b * JS + js) * N_PTS + i_out) * 16 + r;
    #pragma unroll
    for (int e = 0; e < 4; ++e) dst[(size_t)e * 16] = acc[e];
}

// gl GEMM body, BM=64 (rounds 14-19 validated) -------------------------------
template<bool OUTT>
__device__ __forceinline__ void gl_body(
    const short* __restrict__ Wb, const short* __restrict__ XT,
    const float* __restrict__ bias, const float* __restrict__ scale,
    const float* __restrict__ shift, void* __restrict__ Yv,
    int M, int Kp, int ostride, size_t ybs,
    int m0, int n0, int b, int tid, char* smem)
{
    constexpr int BK = 64;
    short (*Wl)[64][BK] = (short(*)[64][BK])smem;              // 16 KB
    short (*Xl)[64][BK] = (short(*)[64][BK])(smem + 16384);    // 16 KB

    const int lane = tid & 63, wave = tid >> 6;
    const int g = lane >> 4, r = lane & 15;
    const int wr = wave >> 1, wc = wave & 1;
    const int wm0 = wr * 32, wn0 = wc * 32;
    const int NT = Kp / BK;

    const int lrow8 = lane >> 3;
    const int lchunk = lane & 7;

    f32x4 acc[2][2];
    #pragma unroll
    for (int i = 0; i < 2; ++i)
        #pragma unroll
        for (int j = 0; j < 2; ++j) acc[i][j] = (f32x4){0.f,0.f,0.f,0.f};

    auto stage = [&](int t, int nb) {
        #pragma unroll
        for (int i = 0; i < 2; ++i) {
            int row0 = wave * 16 + i * 8;
            int row = row0 + lrow8;
            int cl = lchunk ^ (row & 7);
            gload_lds16(&Wb[(size_t)(m0 + row) * Kp + t * BK + cl * 8],
                        &Wl[nb][row0][0]);
            gload_lds16(&XT[((size_t)b * N_PTS + n0 + row) * Kp + t * BK + cl * 8],
                        &Xl[nb][row0][0]);
        }
    };
    auto compute = [&](int cb) {
        #pragma unroll
        for (int q = 0; q < 2; ++q) {
            const int pc = ((q * 4 + g) ^ (r & 7)) * 8;
            #pragma unroll
            for (int fn = 0; fn < 2; ++fn) {
                bf16x8 bb = *(const bf16x8*)&Xl[cb][wn0 + fn * 16 + r][pc];
                #pragma unroll
                for (int fm = 0; fm < 2; ++fm) {
                    bf16x8 a = *(const bf16x8*)&Wl[cb][wm0 + fm * 16 + r][pc];
                    acc[fm][fn] = __builtin_amdgcn_mfma_f32_16x16x32_f16(
                        __builtin_bit_cast(f16x8, a),
                        __builtin_bit_cast(f16x8, bb),
                        acc[fm][fn], 0, 0, 0);
                }
            }
        }
    };

    stage(0, 0);
    __syncthreads();
    for (int t = 0; t < NT; ++t) {
        int cb = t & 1;
        if (t + 1 < NT) stage(t + 1, cb ^ 1);
        compute(cb);
        __syncthreads();
    }

    if constexpr (OUTT) {
        short* Y = (short*)Yv;
        #pragma unroll
        for (int fm = 0; fm < 2; ++fm) {
            int mb = m0 + wm0 + fm * 16 + g * 4;
            if (mb < M) {
                float4 b4 = *(const float4*)&bias[mb];
                float4 s4 = *(const float4*)&scale[mb];
                float4 h4 = *(const float4*)&shift[mb];
                #pragma unroll
                for (int fn = 0; fn < 2; ++fn) {
                    int n = n0 + wn0 + fn * 16 + r;
                    f32x4 a = acc[fm][fn];
                    bf16x4 o;
                    o[0] = f2h(fmaxf(fmaf(a[0] + b4.x, s4.x, h4.x), 0.f));
                    o[1] = f2h(fmaxf(fmaf(a[1] + b4.y, s4.y, h4.y), 0.f));
                    o[2] = f2h(fmaxf(fmaf(a[2] + b4.z, s4.z, h4.z), 0.f));
                    o[3] = f2h(fmaxf(fmaf(a[3] + b4.w, s4.w, h4.w), 0.f));
                    *(bf16x4*)&Y[((size_t)b * N_PTS + n) * ostride + mb] = o;
                }
            }
        }
    } else {
        float* Y = (float*)Yv;
        #pragma unroll
        for (int fm = 0; fm < 2; ++fm) {
            int mbase = m0 + wm0 + fm * 16 + g * 4;
            #pragma unroll
            for (int e = 0; e < 4; ++e) {
                int mm = mbase + e;
                if (mm >= M) continue;
                float bs = bias[mm], sc = scale[mm], sh = shift[mm];
                #pragma unroll
                for (int fn = 0; fn < 2; ++fn) {
                    int n = n0 + wn0 + fn * 16 + r;
                    float v = fmaxf(fmaf(acc[fm][fn][e] + bs, sc, sh), 0.f);
                    Y[(size_t)b * ybs + (size_t)mm * N_PTS + n] = v;
                }
            }
        }
    }
}

// gl GEMM body, BM=128 (r11-validated 4-wave 64m x 32n mapping + gl staging).
// All row offsets multiples of 8 -> same row&7 / r&7 XOR bijection.
__device__ __forceinline__ void gl128_body(
    const short* __restrict__ Wb, const short* __restrict__ XT,
    const float* __restrict__ bias, const float* __restrict__ scale,
    const float* __restrict__ shift, short* __restrict__ Y,
    int M, int Kp, int ostride,
    int m0, int n0, int b, int tid, char* smem)
{
    constexpr int BK = 64;
    short (*Wl)[128][BK] = (short(*)[128][BK])smem;             // 32 KB
    short (*Xl)[64][BK] = (short(*)[64][BK])(smem + 32768);     // 16 KB

    const int lane = tid & 63, wave = tid >> 6;
    const int g = lane >> 4, r = lane & 15;
    const int wr = wave >> 1, wc = wave & 1;
    const int wm0 = wr * 64, wn0 = wc * 32;
    const int NT = Kp / BK;

    const int lrow8 = lane >> 3;
    const int lchunk = lane & 7;

    f32x4 acc[4][2];
    #pragma unroll
    for (int i = 0; i < 4; ++i)
        #pragma unroll
        for (int j = 0; j < 2; ++j) acc[i][j] = (f32x4){0.f,0.f,0.f,0.f};

    auto stage = [&](int t, int nb) {
        #pragma unroll
        for (int i = 0; i < 4; ++i) {            // W: 128 rows
            int row0 = wave * 32 + i * 8;
            int row = row0 + lrow8;
            int cl = lchunk ^ (row & 7);
            gload_lds16(&Wb[(size_t)(m0 + row) * Kp + t * BK + cl * 8],
                        &Wl[nb][row0][0]);
        }
        #pragma unroll
        for (int i = 0; i < 2; ++i) {            // X: 64 rows
            int row0 = wave * 16 + i * 8;
            int row = row0 + lrow8;
            int cl = lchunk ^ (row & 7);
            gload_lds16(&XT[((size_t)b * N_PTS + n0 + row) * Kp + t * BK + cl * 8],
                        &Xl[nb][row0][0]);
        }
    };
    auto compute = [&](int cb) {
        #pragma unroll
        for (int q = 0; q < 2; ++q) {
            const int pc = ((q * 4 + g) ^ (r & 7)) * 8;
            #pragma unroll
            for (int fn = 0; fn < 2; ++fn) {
                bf16x8 bb = *(const bf16x8*)&Xl[cb][wn0 + fn * 16 + r][pc];
                #pragma unroll
                for (int fm = 0; fm < 4; ++fm) {
                    bf16x8 a = *(const bf16x8*)&Wl[cb][wm0 + fm * 16 + r][pc];
                    acc[fm][fn] = __builtin_amdgcn_mfma_f32_16x16x32_f16(
                        __builtin_bit_cast(f16x8, a),
                        __builtin_bit_cast(f16x8, bb),
                        acc[fm][fn], 0, 0, 0);
                }
            }
        }
    };

    stage(0, 0);
    __syncthreads();
    for (int t = 0; t < NT; ++t) {
        int cb = t & 1;
        if (t + 1 < NT) stage(t + 1, cb ^ 1);
        compute(cb);
        __syncthreads();
    }

    #pragma unroll
    for (int fm = 0; fm < 4; ++fm) {
        int mb = m0 + wm0 + fm * 16 + g * 4;
        if (mb < M) {
            float4 b4 = *(const float4*)&bias[mb];
            float4 s4 = *(const float4*)&scale[mb];
            float4 h4 = *(const float4*)&shift[mb];
            #pragma unroll
            for (int fn = 0; fn < 2; ++fn) {
                int n = n0 + wn0 + fn * 16 + r;
                f32x4 a = acc[fm][fn];
                bf16x4 o;
                o[0] = f2h(fmaxf(fmaf(a[0] + b4.x, s4.x, h4.x), 0.f));
                o[1] = f2h(fmaxf(fmaf(a[1] + b4.y, s4.y, h4.y), 0.f));
                o[2] = f2h(fmaxf(fmaf(a[2] + b4.z, s4.z, h4.z), 0.f));
                o[3] = f2h(fmaxf(fmaf(a[3] + b4.w, s4.w, h4.w), 0.f));
                *(bf16x4*)&Y[((size_t)b * N_PTS + n) * ostride + mb] = o;
            }
        }
    }
}

// eigen finalize body (round-9 validated) ------------------------------------
__device__ __forceinline__ void finalize_body(
    const float* __restrict__ xyz, const float* __restrict__ pbuf,
    const float* __restrict__ ew1, const float* __restrict__ eb1,
    const float* __restrict__ ew2, const float* __restrict__ eb2,
    short* __restrict__ zinT, float* __restrict__ out, int bx, int tid)
{
    int id = bx * 256 + tid;
    if (id >= BATCH * N_PTS) return;
    int b = id >> 12, i = id & (N_PTS - 1);

    out[id*3+0] = xyz[id*3+0];
    out[id*3+1] = xyz[id*3+1];
    out[id*3+2] = xyz[id*3+2];

    double s[10] = {0,0,0,0,0,0,0,0,0,0};
    for (int js = 0; js < JS; ++js) {
        const float* src = pbuf + ((size_t)(b * JS + js) * N_PTS + i) * 16;
        #pragma unroll
        for (int q = 0; q < 10; ++q) s[q] += (double)src[q];
    }
    const float* xb = xyz + (size_t)b * N_PTS * 3;
    float xi = xb[i*3+0], yi = xb[i*3+1], zi = xb[i*3+2];
    s[0] -= 1.0;
    s[1] -= (double)(float)(_Float16)xi;
    s[2] -= (double)(float)(_Float16)yi;
    s[3] -= (double)(float)(_Float16)zi;
    s[4] -= (double)(float)(_Float16)(xi * xi);
    s[5] -= (double)(float)(_Float16)(xi * yi);
    s[6] -= (double)(float)(_Float16)(xi * zi);
    s[7] -= (double)(float)(_Float16)(yi * yi);
    s[8] -= (double)(float)(_Float16)(yi * zi);
    s[9] -= (double)(float)(_Float16)(zi * zi);

    double cnt = s[0];
    double denom = fmax(cnt, 1.0);
    double mx = s[1] / denom, my = s[2] / denom, mz = s[3] / denom;
    const double invN = 1.0 / (double)N_PTS;
    double c00 = (s[4] - cnt * mx * mx) * invN;
    double c01 = (s[5] - cnt * mx * my) * invN;
    double c02 = (s[6] - cnt * mx * mz) * invN;
    double c11 = (s[7] - cnt * my * my) * invN;
    double c12 = (s[8] - cnt * my * mz) * invN;
    double c22 = (s[9] - cnt * mz * mz) * invN;

    double qm = (c00 + c11 + c22) / 3.0;
    double p1 = c01*c01 + c02*c02 + c12*c12;
    double a0 = c00 - qm, a1 = c11 - qm, a2 = c22 - qm;
    double p2 = a0*a0 + a1*a1 + a2*a2 + 2.0*p1;
    double e_lo, e_mid, e_hi;
    if (p2 < 1e-32) {
        e_lo = e_mid = e_hi = qm;
    } else {
        double p = sqrt(p2 / 6.0);
        double inv = 1.0 / p;
        double b00 = a0*inv, b11 = a1*inv, b22 = a2*inv;
        double b01 = c01*inv, b02 = c02*inv, b12 = c12*inv;
        double detB = b00*(b11*b22 - b12*b12)
                    - b01*(b01*b22 - b12*b02)
                    + b02*(b01*b12 - b11*b02);
        double r = 0.5 * detB;
        r = fmin(1.0, fmax(-1.0, r));
        double phi = acos(r) / 3.0;
        double two_p = 2.0 * p;
        e_hi = qm + two_p * cos(phi);
        e_lo = qm + two_p * cos(phi + 2.0943951023931953);
        e_mid = 3.0 * qm - e_hi - e_lo;
    }
    float e0 = (float)e_lo, e1 = (float)e_mid, e2 = (float)e_hi;

    float t[4];
    #pragma unroll
    for (int o = 0; o < 4; ++o)
        t[o] = fmaxf(e0 * ew1[o*3+0] + e1 * ew1[o*3+1] +
                     e2 * ew1[o*3+2] + eb1[o], 0.f);
    bf16x4 ov;
    #pragma unroll
    for (int o = 0; o < 4; ++o) {
        float h = t[0]*ew2[o*4+0] + t[1]*ew2[o*4+1] +
                  t[2]*ew2[o*4+2] + t[3]*ew2[o*4+3] + eb2[o];
        ov[o] = f2h(h);
    }
    *(bf16x4*)&zinT[((size_t)b * N_PTS + i) * 192 + 160] = ov;
}

// DG2+DG3 fused body (round-16 validated) ------------------------------------
__device__ __forceinline__ void dg23_body(
    const short* __restrict__ W2b, const short* __restrict__ W3b,
    const short* __restrict__ XT,
    const float* __restrict__ cb2, const float* __restrict__ cs2,
    const float* __restrict__ ct2,
    const float* __restrict__ cb3, const float* __restrict__ cs3,
    const float* __restrict__ ct3,
    short* __restrict__ zinT, int x, int b, int tid, char* smem)
{
    constexpr int BK = 64;
    short (*Wl)[64][64] = (short(*)[64][64])smem;
    short (*Xl)[64][64] = (short(*)[64][64])(smem + 16384);
    short (*Wl3)[72] = (short(*)[72])(smem + 32768);
    short (*Xl3)[72] = (short(*)[72])(smem + 32768 + 9216);

    const int lane = tid & 63, wave = tid >> 6;
    const int g = lane >> 4, r = lane & 15;
    const int wr = wave >> 1, wc = wave & 1;
    const int wm0 = wr * 32, wn0 = wc * 32;
    const int n0 = x * 64;
    const int Kp = 256, NT = 4;

    const int lrow8 = lane >> 3;
    const int lchunk = lane & 7;

    #pragma unroll
    for (int u = 0; u < 2; ++u) {
        int id = u * 256 + tid;
        int m = id >> 3, c = id & 7;
        *(bf16x8*)&Wl3[m][c * 8] = *(const bf16x8*)&W3b[(size_t)m * 64 + c * 8];
    }

    f32x4 acc[2][2];
    #pragma unroll
    for (int i = 0; i < 2; ++i)
        #pragma unroll
        for (int j = 0; j < 2; ++j) acc[i][j] = (f32x4){0.f,0.f,0.f,0.f};

    auto stage = [&](int t, int nb) {
        #pragma unroll
        for (int i = 0; i < 2; ++i) {
            int row0 = wave * 16 + i * 8;
            int row = row0 + lrow8;
            int cl = lchunk ^ (row & 7);
            gload_lds16(&W2b[(size_t)row * Kp + t * BK + cl * 8],
                        &Wl[nb][row0][0]);
            gload_lds16(&XT[((size_t)b * N_PTS + n0 + row) * Kp + t * BK + cl * 8],
                        &Xl[nb][row0][0]);
        }
    };
    auto compute = [&](int cb) {
        #pragma unroll
        for (int q = 0; q < 2; ++q) {
            const int pc = ((q * 4 + g) ^ (r & 7)) * 8;
            #pragma unroll
            for (int fn = 0; fn < 2; ++fn) {
                bf16x8 bb = *(const bf16x8*)&Xl[cb][wn0 + fn * 16 + r][pc];
                #pragma unroll
                for (int fm = 0; fm < 2; ++fm) {
                    bf16x8 a = *(const bf16x8*)&Wl[cb][wm0 + fm * 16 + r][pc];
                    acc[fm][fn] = __builtin_amdgcn_mfma_f32_16x16x32_f16(
                        __builtin_bit_cast(f16x8, a),
                        __builtin_bit_cast(f16x8, bb),
                        acc[fm][fn], 0, 0, 0);
                }
            }
        }
    };

    stage(0, 0);
    __syncthreads();
    for (int t = 0; t < NT; ++t) {
        int cb = t & 1;
        if (t + 1 < NT) stage(t + 1, cb ^ 1);
        compute(cb);
        __syncthreads();
    }

    #pragma unroll
    for (int fm = 0; fm < 2; ++fm) {
        int mb = wm0 + fm * 16 + g * 4;
        float4 b4 = *(const float4*)&cb2[mb];
        float4 s4 = *(const float4*)&cs2[mb];
        float4 h4 = *(const float4*)&ct2[mb];
        #pragma unroll
        for (int fn = 0; fn < 2; ++fn) {
            int nl = wn0 + fn * 16 + r;
            f32x4 a = acc[fm][fn];
            bf16x4 o;
            o[0] = f2h(fmaxf(fmaf(a[0] + b4.x, s4.x, h4.x), 0.f));
            o[1] = f2h(fmaxf(fmaf(a[1] + b4.y, s4.y, h4.y), 0.f));
            o[2] = f2h(fmaxf(fmaf(a[2] + b4.z, s4.z, h4.z), 0.f));
            o[3] = f2h(fmaxf(fmaf(a[3] + b4.w, s4.w, h4.w), 0.f));
            *(bf16x4*)&Xl3[nl][mb] = o;
        }
    }
    __syncthreads();

    f32x4 acc3[2][2];
    #pragma unroll
    for (int i = 0; i < 2; ++i)
        #pragma unroll
        for (int j = 0; j < 2; ++j) acc3[i][j] = (f32x4){0.f,0.f,0.f,0.f};
    #pragma unroll
    for (int q = 0; q < 2; ++q) {
        #pragma unroll
        for (int fn = 0; fn < 2; ++fn) {
            bf16x8 bb = *(const bf16x8*)&Xl3[wn0 + fn * 16 + r][q * 32 + g * 8];
            #pragma unroll
            for (int fm = 0; fm < 2; ++fm) {
                bf16x8 a = *(const bf16x8*)&Wl3[wm0 + fm * 16 + r][q * 32 + g * 8];
                acc3[fm][fn] = __builtin_amdgcn_mfma_f32_16x16x32_f16(
                    __builtin_bit_cast(f16x8, a),
                    __builtin_bit_cast(f16x8, bb),
                    acc3[fm][fn], 0, 0, 0);
            }
        }
    }

    #pragma unroll
    for (int fm = 0; fm < 2; ++fm) {
        int mb = wm0 + fm * 16 + g * 4;
        if (mb < 32) {
            float4 b4 = *(const float4*)&cb3[mb];
            float4 s4 = *(const float4*)&cs3[mb];
            float4 h4 = *(const float4*)&ct3[mb];
            #pragma unroll
            for (int fn = 0; fn < 2; ++fn) {
                int n = n0 + wn0 + fn * 16 + r;
                f32x4 a = acc3[fm][fn];
                bf16x4 o;
                o[0] = f2h(fmaxf(fmaf(a[0] + b4.x, s4.x, h4.x), 0.f));
                o[1] = f2h(fmaxf(fmaf(a[1] + b4.y, s4.y, h4.y), 0.f));
                o[2] = f2h(fmaxf(fmaf(a[2] + b4.z, s4.z, h4.z), 0.f));
                o[3] = f2h(fmaxf(fmaf(a[3] + b4.w, s4.w, h4.w), 0.f));
                *(bf16x4*)&zinT[((size_t)b * N_PTS + n) * 192 + 128 + mb] = o;
            }
        }
    }
}

// ===========================================================================
// Mega-kernels
// ===========================================================================

// megaA: transposes (long pole, first) || radius || wconv
__global__ __launch_bounds__(256) void megaA_kernel(
    WcArgs wa,
    const float* __restrict__ xyz, float* __restrict__ pmax,
    const float* __restrict__ h2, const float* __restrict__ h1,
    short* __restrict__ t_h2, short* __restrict__ zinT)
{
    __shared__ __align__(16) char smem[32768];   // max(transpose64 32K, radius 8.2K)
    const int tid = threadIdx.x;
    int bx = blockIdx.x;
    const int nTrans = 64 * 9 * BATCH;           // 2304
    if (bx < nTrans) {
        int x = bx & 63, rest = bx >> 6;
        int y = rest % 9, b = rest / 9;
        transpose64_body(h2, h1, t_h2, zinT, x, y, b, tid, smem);
        return;
    }
    bx -= nTrans;
    if (bx < 2048) {
        int ci = bx & 63, js = (bx >> 6) & 7, b = bx >> 9;
        radius_body(xyz, pmax, ci, js, b, tid, smem);
        return;
    }
    bx -= 2048;
    wconv_body(wa, bx, tid);
}

// megaB: eigen_accum || DG1
__global__ __launch_bounds__(256) void megaB_kernel(
    const float* __restrict__ xyz, const float* __restrict__ pmax,
    float* __restrict__ pbuf,
    const short* __restrict__ wb1, const short* __restrict__ t_h2,
    const float* __restrict__ db1, const float* __restrict__ ds1,
    const float* __restrict__ dt1, short* __restrict__ bufA)
{
    __shared__ __align__(16) char smem[32768];
    const int tid = threadIdx.x;
    int bx = blockIdx.x;
    if (bx < 2048) {
        int ci = bx & 63, js = (bx >> 6) & 7, b = bx >> 9;
        accum_body(xyz, pmax, pbuf, ci, js, b, tid, smem);
    } else {
        int e = bx - 2048;
        int x = e & 63, my = (e >> 6) & 3, b = e >> 8;
        gl_body<true>(wb1, t_h2, db1, ds1, dt1, bufA,
                      256, 1024, 256, 0, my * 64, x * 64, b, tid, smem);
    }
}

// megaC: finalize || dg23
__global__ __launch_bounds__(256) void megaC_kernel(
    const float* __restrict__ xyz, const float* __restrict__ pbuf,
    const float* __restrict__ ew1, const float* __restrict__ eb1,
    const float* __restrict__ ew2, const float* __restrict__ eb2,
    float* __restrict__ out,
    const short* __restrict__ wb2, const short* __restrict__ wb3,
    const short* __restrict__ bufA,
    const float* __restrict__ cb2, const float* __restrict__ cs2,
    const float* __restrict__ ct2,
    const float* __restrict__ cb3, const float* __restrict__ cs3,
    const float* __restrict__ ct3,
    short* __restrict__ zinT)
{
    __shared__ __align__(16) char smem[51200];
    const int tid = threadIdx.x;
    int bx = blockIdx.x;
    if (bx < 64) {
        finalize_body(xyz, pbuf, ew1, eb1, ew2, eb2, zinT, out, bx, tid);
    } else {
        int e = bx - 64;
        int x = e & 63, b = e >> 6;
        dg23_body(wb2, wb3, bufA, cb2, cs2, ct2, cb3, cs3, ct3,
                  zinT, x, b, tid, smem);
    }
}

// standalone gl GEMM BM=64 (F2, F3)
template<bool OUTT>
__global__ __launch_bounds__(256) void mfma_gemm_gl(
    const short* __restrict__ Wb, const short* __restrict__ XT,
    const float* __restrict__ bias, const float* __restrict__ scale,
    const float* __restrict__ shift, void* __restrict__ Yv,
    int M, int Kp, int ostride, size_t ybs)
{
    __shared__ __align__(16) char smem[32768];
    gl_body<OUTT>(Wb, XT, bias, scale, shift, Yv, M, Kp, ostride, ybs,
                  blockIdx.y * 64, blockIdx.x * 64, blockIdx.z,
                  threadIdx.x, smem);
}

// standalone gl GEMM BM=128 (F1)
__global__ __launch_bounds__(256) void mfma_gemm_gl128(
    const short* __restrict__ Wb, const short* __restrict__ XT,
    const float* __restrict__ bias, const float* __restrict__ scale,
    const float* __restrict__ shift, short* __restrict__ Y,
    int M, int Kp, int ostride)
{
    __shared__ __align__(16) char smem[49152];
    gl128_body(Wb, XT, bias, scale, shift, Y, M, Kp, ostride,
               blockIdx.y * 128, blockIdx.x * 64, blockIdx.z,
               threadIdx.x, smem);
}

// ---------------------------------------------------------------------------
extern "C" void kernel_launch(void* const* d_in, const int* in_sizes, int n_in,
                              void* d_out, int out_size, void* d_ws, size_t ws_size,
                              hipStream_t stream)
{
    const float* xyz   = (const float*)d_in[0];
    const float* h1    = (const float*)d_in[1];
    const float* h2_in = (const float*)d_in[2];
    const float* dg_w1 = (const float*)d_in[3];
    const float* dg_b1 = (const float*)d_in[4];
    const float* dg_s1 = (const float*)d_in[5];
    const float* dg_t1 = (const float*)d_in[6];
    const float* dg_w2 = (const float*)d_in[7];
    const float* dg_b2 = (const float*)d_in[8];
    const float* dg_s2 = (const float*)d_in[9];
    const float* dg_t2 = (const float*)d_in[10];
    const float* dg_w3 = (const float*)d_in[11];
    const float* dg_b3 = (const float*)d_in[12];
    const float* dg_s3 = (const float*)d_in[13];
    const float* dg_t3 = (const float*)d_in[14];
    const float* ed_w1 = (const float*)d_in[15];
    const float* ed_b1 = (const float*)d_in[16];
    const float* ed_w2 = (const float*)d_in[17];
    const float* ed_b2 = (const float*)d_in[18];
    const float* w1 = (const float*)d_in[19];
    const float* b1 = (const float*)d_in[20];
    const float* s1 = (const float*)d_in[21];
    const float* t1 = (const float*)d_in[22];
    const float* w2 = (const float*)d_in[23];
    const float* b2 = (const float*)d_in[24];
    const float* s2 = (const float*)d_in[25];
    const float* t2 = (const float*)d_in[26];
    const float* w3 = (const float*)d_in[27];
    const float* b3 = (const float*)d_in[28];
    const float* s3 = (const float*)d_in[29];
    const float* t3 = (const float*)d_in[30];

    float* out = (float*)d_out;

    char* ws = (char*)d_ws;
    size_t off = 0;
    auto alloc = [&](size_t bytes) {
        char* p = ws + off;
        off += (bytes + 255) & ~(size_t)255;
        return p;
    };
    float* pmax = (float*)alloc((size_t)BATCH * JS * 64 * 4);       // 8 KB
    short* wb1  = (short*)alloc((size_t)256 * 1024 * 2);
    short* wb2  = (short*)alloc((size_t)64  * 256  * 2);
    short* wb3  = (short*)alloc((size_t)64  * 64   * 2);
    short* wbf1 = (short*)alloc((size_t)512 * 192  * 2);
    short* wbf2 = (short*)alloc((size_t)256 * 512  * 2);
    short* wbf3 = (short*)alloc((size_t)128 * 256  * 2);
    short* zinT = (short*)alloc((size_t)BATCH * N_PTS * 192 * 2);   // 6.3 MB
    short* t_h2 = (short*)alloc((size_t)BATCH * N_PTS * 1024 * 2);  // 33.5 MB
    short* bufA = (short*)alloc((size_t)BATCH * N_PTS * 256 * 2);   // 8.4 MB
    float* pbuf = (float*)alloc((size_t)BATCH * JS * N_PTS * 16 * 4); // 8.4 MB
    short* bufB = t_h2;   // [B][N][512] fp16 (t_h2 dead after DG1)
    short* bufD = bufA;   // [B][N][256] fp16 (bufA dead after dg23)

    WcArgs wa;
    int wcTotal;
    {
        const float* Wp[6] = {dg_w1, dg_w2, dg_w3, w1, w2, w3};
        short* Op[6] = {wb1, wb2, wb3, wbf1, wbf2, wbf3};
        int Mv[6] = {256, 64, 32, 512, 256, 128};
        int Kv[6] = {1024, 256, 64, 164, 512, 256};
        int Mp[6] = {256, 64, 64, 512, 256, 128};
        int Kp[6] = {1024, 256, 64, 192, 512, 256};
        int acc0 = 0;
        for (int l = 0; l < 6; ++l) {
            wa.W[l] = Wp[l]; wa.O[l] = Op[l];
            wa.M[l] = Mv[l]; wa.K[l] = Kv[l]; wa.Kp[l] = Kp[l];
            wa.start[l] = acc0;
            acc0 += Mp[l] * Kp[l];
        }
        wa.start[6] = acc0;
        wcTotal = acc0;
    }
    const int wcBlocks = (wcTotal + 255) / 256;

    {
        int grid = 64 * 9 * BATCH + 2048 + wcBlocks;
        megaA_kernel<<<grid, 256, 0, stream>>>(
            wa, xyz, pmax, h2_in, h1, t_h2, zinT);
    }
    megaB_kernel<<<2048 + 64 * 4 * BATCH, 256, 0, stream>>>(
        xyz, pmax, pbuf, wb1, t_h2, dg_b1, dg_s1, dg_t1, bufA);
    megaC_kernel<<<64 + 64 * BATCH, 256, 0, stream>>>(
        xyz, pbuf, ed_w1, ed_b1, ed_w2, ed_b2, out,
        wb2, wb3, bufA, dg_b2, dg_s2, dg_t2, dg_b3, dg_s3, dg_t3, zinT);

    // F1: 192 -> 512 (BM=128 variant)
    mfma_gemm_gl128<<<dim3(N_PTS/64, 4, BATCH), 256, 0, stream>>>(
        wbf1, zinT, b1, s1, t1, bufB, 512, 192, 512);
    // F2: 512 -> 256
    mfma_gemm_gl<true><<<dim3(N_PTS/64, 4, BATCH), 256, 0, stream>>>(
        wbf2, bufB, b2, s2, t2, bufD, 256, 512, 256, 0);
    // F3: 256 -> 128 (f32 [b][m][n] into d_out after xyz)
    mfma_gemm_gl<false><<<dim3(N_PTS/64, 2, BATCH), 256, 0, stream>>>(
        wbf3, bufD, b3, s3, t3, out + (size_t)BATCH * N_PTS * 3, 128, 256, 0,
        (size_t)128 * N_PTS);
}

// Round 21
// 100.691 us; speedup vs baseline: 1.0944x; 1.0944x over previous
//
#include <hip/hip_runtime.h>
#include <math.h>

#define N_PTS 4096
#define BATCH 4
#define JS 8                  // j-split factor
#define JCH (N_PTS / JS)      // 512 points per j-chunk

typedef short bf16x8 __attribute__((ext_vector_type(8)));
typedef short bf16x4 __attribute__((ext_vector_type(4)));
typedef float f32x4 __attribute__((ext_vector_type(4)));
typedef _Float16 f16x8 __attribute__((ext_vector_type(8)));

__device__ inline short f2h(float f) {
    _Float16 h = (_Float16)f;
    return __builtin_bit_cast(short, h);
}

__device__ inline void gload_lds16(const void* g, void* l) {
    __builtin_amdgcn_global_load_lds(
        (const __attribute__((address_space(1))) unsigned int*)g,
        (__attribute__((address_space(3))) unsigned int*)l, 16, 0, 0);
}

// ---------------------------------------------------------------------------
// Weight-conversion args (6 layers)
// ---------------------------------------------------------------------------
struct WcArgs {
    const float* W[6];
    short* O[6];
    int M[6], K[6], Kp[6];
    int start[7];
};

// ===========================================================================
// Device bodies (math identical to rounds 14-17 validated kernels)
// ===========================================================================

// wconv body -----------------------------------------------------------------
__device__ __forceinline__ void wconv_body(const WcArgs& a, int bx, int tid)
{
    int id = bx * 256 + tid;
    if (id >= a.start[6]) return;
    int l = 0;
    #pragma unroll
    for (int q = 1; q < 6; ++q) if (id >= a.start[q]) l = q;
    int local = id - a.start[l];
    int kp = a.Kp[l];
    int mrow = local / kp, k = local - mrow * kp;
    float v = (mrow < a.M[l] && k < a.K[l]) ? a.W[l][(size_t)mrow * a.K[l] + k] : 0.f;
    a.O[l][local] = f2h(v);
}

// radius body (triangular; per-block partial max, no atomics) ----------------
__device__ __forceinline__ void radius_body(
    const float* __restrict__ xyz, float* __restrict__ pmax,
    int ci, int js, int b, int tid, char* smem)
{
    if (ci >= 8 * js + 8) return;              // uniform triangular exit
    float4* sj = (float4*)smem;                // JCH*16 = 8 KB
    float* wred = (float*)(smem + JCH * 16);
    const float* xb = xyz + (size_t)b * N_PTS * 3;
    const int j0 = js * JCH;
    for (int idx = tid; idx < JCH; idx += 256) {
        int j = j0 + idx;
        float x = xb[j*3+0], y = xb[j*3+1], z = xb[j*3+2];
        sj[idx] = make_float4(x, y, z, fmaf(x, x, fmaf(y, y, z * z)));
    }
    __syncthreads();
    const int il = tid & 63;
    const int jq = tid >> 6;
    const int i = ci * 64 + il;
    const float xi = xb[i*3+0], yi = xb[i*3+1], zi = xb[i*3+2];
    const float x2i = fmaf(xi, xi, fmaf(yi, yi, zi * zi));
    float m = 0.f;
    const int jb = jq * (JCH / 4);
    #pragma unroll 4
    for (int j = jb; j < jb + JCH / 4; ++j) {
        float4 p = sj[j];
        float dot = fmaf(xi, p.x, fmaf(yi, p.y, zi * p.z));
        float d2 = fmaf(-2.f, dot, x2i + p.w);
        m = fmaxf(m, d2);
    }
    for (int off = 32; off >= 1; off >>= 1) m = fmaxf(m, __shfl_down(m, off));
    if ((tid & 63) == 0) wred[tid >> 6] = m;
    __syncthreads();
    if (tid == 0) {
        float mm = fmaxf(fmaxf(wred[0], wred[1]), fmaxf(wred[2], wred[3]));
        pmax[((size_t)b * JS + js) * 64 + ci] = mm;
    }
}

// transpose body, VECTORIZED (r19-validated): float4 loads, bf16x8 stores,
// XOR-swizzled pad-free [128][32] tile. Element (c,n) lives at
// tile[c][n ^ (4*((c>>3)&7))] (same involution on write and read).
__device__ __forceinline__ void transpose_body(
    const float* __restrict__ h2, const float* __restrict__ h1,
    short* __restrict__ t_h2, short* __restrict__ zinT,
    int x, int y, int b, int tid, char* smem)
{
    float (*tile)[32] = (float(*)[32])smem;    // 16 KB
    const int n0 = x * 32;
    const float* src = (y < 8)
        ? h2 + ((size_t)b * 1024 + y * 128) * N_PTS
        : h1 + (size_t)b * 128 * N_PTS;
    // load: 128 rows x 8 float4 = 1024 quads, 4 iters
    #pragma unroll
    for (int it = 0; it < 4; ++it) {
        int idx = it * 256 + tid;
        int c = idx >> 3, q = idx & 7;
        int sw = (q ^ ((c >> 3) & 7)) * 4;
        *(float4*)&tile[c][sw] = *(const float4*)&src[(size_t)c * N_PTS + n0 + q * 4];
    }
    __syncthreads();
    // write: 32 n x 16 channel-groups(8) = 512, 2 iters
    if (y < 8) {
        const int c0 = y * 128;
        #pragma unroll
        for (int it = 0; it < 2; ++it) {
            int idx = it * 256 + tid;
            int n = idx >> 4, cg = idx & 15;
            bf16x8 v;
            #pragma unroll
            for (int j = 0; j < 8; ++j) {
                int c = cg * 8 + j;
                v[j] = f2h(tile[c][n ^ (4 * ((c >> 3) & 7))]);
            }
            *(bf16x8*)&t_h2[((size_t)b * N_PTS + n0 + n) * 1024 + c0 + cg * 8] = v;
        }
    } else {
        #pragma unroll
        for (int it = 0; it < 2; ++it) {
            int idx = it * 256 + tid;
            int n = idx >> 4, cg = idx & 15;
            bf16x8 v;
            #pragma unroll
            for (int j = 0; j < 8; ++j) {
                int c = cg * 8 + j;
                v[j] = f2h(tile[c][n ^ (4 * ((c >> 3) & 7))]);
            }
            *(bf16x8*)&zinT[((size_t)b * N_PTS + n0 + n) * 192 + cg * 8] = v;
        }
        for (int idx = tid; idx < 32 * 7; idx += 256) {
            int n = idx / 7, cq = 164 + (idx % 7) * 4;
            bf16x4 z = {0, 0, 0, 0};
            *(bf16x4*)&zinT[((size_t)b * N_PTS + n0 + n) * 192 + cq] = z;
        }
    }
}

// eigen accumulate body (MFMA mask GEMM; r2 from exact pmax reduce) ----------
__device__ __forceinline__ void accum_body(
    const float* __restrict__ xyz, const float* __restrict__ pmax,
    float* __restrict__ pbuf, int ci, int js, int b, int tid, char* smem)
{
    float4* sj4 = (float4*)smem;                               // 8 KB
    _Float16 (*Ft)[JCH + 8] = (_Float16(*)[JCH + 8])(smem + 8192);  // 16.25 KB
    float* redbuf = (float*)(smem + 8192 + 16 * (JCH + 8) * 2);

    const int lane = tid & 63, wave = tid >> 6;

    float mval = 0.f;
    for (int e = tid; e < 512; e += 256) {
        int js2 = e >> 6, ci2 = e & 63;
        float v = (ci2 < 8 * js2 + 8) ? pmax[((size_t)b * JS + js2) * 64 + ci2] : 0.f;
        mval = fmaxf(mval, v);
    }
    for (int off = 32; off >= 1; off >>= 1) mval = fmaxf(mval, __shfl_down(mval, off));
    if (lane == 0) redbuf[wave] = mval;

    const float* xb = xyz + (size_t)b * N_PTS * 3;
    const int j0g = js * JCH;
    for (int idx = tid; idx < JCH; idx += 256) {
        int j = j0g + idx;
        float x = xb[j*3+0], y = xb[j*3+1], z = xb[j*3+2];
        sj4[idx] = make_float4(x, y, z, fmaf(x, x, fmaf(y, y, z * z)));
        Ft[0][idx] = (_Float16)1.f;
        Ft[1][idx] = (_Float16)x;
        Ft[2][idx] = (_Float16)y;
        Ft[3][idx] = (_Float16)z;
        Ft[4][idx] = (_Float16)(x * x);
        Ft[5][idx] = (_Float16)(x * y);
        Ft[6][idx] = (_Float16)(x * z);
        Ft[7][idx] = (_Float16)(y * y);
        Ft[8][idx] = (_Float16)(y * z);
        Ft[9][idx] = (_Float16)(z * z);
        Ft[10][idx] = (_Float16)0.f; Ft[11][idx] = (_Float16)0.f;
        Ft[12][idx] = (_Float16)0.f; Ft[13][idx] = (_Float16)0.f;
        Ft[14][idx] = (_Float16)0.f; Ft[15][idx] = (_Float16)0.f;
    }
    __syncthreads();
    const float mm = fmaxf(fmaxf(redbuf[0], redbuf[1]), fmaxf(redbuf[2], redbuf[3]));
    const float r2 = 0.01f * mm;

    const int r = lane & 15, g = lane >> 4;
    const int i_wf = ci * 64 + wave * 16 + r;
    const float xi = xb[i_wf*3+0], yi = xb[i_wf*3+1], zi = xb[i_wf*3+2];
    const float x2i = fmaf(xi, xi, fmaf(yi, yi, zi * zi));

    f32x4 acc = (f32x4){0.f, 0.f, 0.f, 0.f};
    #pragma unroll 4
    for (int t = 0; t < JCH / 32; ++t) {
        const int jb = t * 32 + g * 8;
        f16x8 wfv;
        #pragma unroll
        for (int s = 0; s < 8; ++s) {
            float4 p = sj4[jb + s];
            float dot = fmaf(xi, p.x, fmaf(yi, p.y, zi * p.z));
            float d2 = fmaf(-2.f, dot, x2i + p.w);
            wfv[s] = (d2 < r2) ? (_Float16)1.f : (_Float16)0.f;
        }
        f16x8 fv = *(const f16x8*)&Ft[r][jb];
        acc = __builtin_amdgcn_mfma_f32_16x16x32_f16(wfv, fv, acc, 0, 0, 0);
    }

    const int i_out = ci * 64 + wave * 16 + g * 4;
    float* dst = pbuf + ((size_t)(b * JS + js) * N_PTS + i_out) * 16 + r;
    #pragma unroll
    for (int e = 0; e < 4; ++e) dst[(size_t)e * 16] = acc[e];
}

// gl GEMM body (round-14/15 validated) ---------------------------------------
template<bool OUTT>
__device__ __forceinline__ void gl_body(
    const short* __restrict__ Wb, const short* __restrict__ XT,
    const float* __restrict__ bias, const float* __restrict__ scale,
    const float* __restrict__ shift, void* __restrict__ Yv,
    int M, int Kp, int ostride, size_t ybs,
    int m0, int n0, int b, int tid, char* smem)
{
    constexpr int BK = 64;
    short (*Wl)[64][BK] = (short(*)[64][BK])smem;              // 16 KB
    short (*Xl)[64][BK] = (short(*)[64][BK])(smem + 16384);    // 16 KB

    const int lane = tid & 63, wave = tid >> 6;
    const int g = lane >> 4, r = lane & 15;
    const int wr = wave >> 1, wc = wave & 1;
    const int wm0 = wr * 32, wn0 = wc * 32;
    const int NT = Kp / BK;

    const int lrow8 = lane >> 3;
    const int lchunk = lane & 7;

    f32x4 acc[2][2];
    #pragma unroll
    for (int i = 0; i < 2; ++i)
        #pragma unroll
        for (int j = 0; j < 2; ++j) acc[i][j] = (f32x4){0.f,0.f,0.f,0.f};

    auto stage = [&](int t, int nb) {
        #pragma unroll
        for (int i = 0; i < 2; ++i) {
            int row0 = wave * 16 + i * 8;
            int row = row0 + lrow8;
            int cl = lchunk ^ (row & 7);
            gload_lds16(&Wb[(size_t)(m0 + row) * Kp + t * BK + cl * 8],
                        &Wl[nb][row0][0]);
            gload_lds16(&XT[((size_t)b * N_PTS + n0 + row) * Kp + t * BK + cl * 8],
                        &Xl[nb][row0][0]);
        }
    };
    auto compute = [&](int cb) {
        #pragma unroll
        for (int q = 0; q < 2; ++q) {
            const int pc = ((q * 4 + g) ^ (r & 7)) * 8;
            #pragma unroll
            for (int fn = 0; fn < 2; ++fn) {
                bf16x8 bb = *(const bf16x8*)&Xl[cb][wn0 + fn * 16 + r][pc];
                #pragma unroll
                for (int fm = 0; fm < 2; ++fm) {
                    bf16x8 a = *(const bf16x8*)&Wl[cb][wm0 + fm * 16 + r][pc];
                    acc[fm][fn] = __builtin_amdgcn_mfma_f32_16x16x32_f16(
                        __builtin_bit_cast(f16x8, a),
                        __builtin_bit_cast(f16x8, bb),
                        acc[fm][fn], 0, 0, 0);
                }
            }
        }
    };

    stage(0, 0);
    __syncthreads();
    for (int t = 0; t < NT; ++t) {
        int cb = t & 1;
        if (t + 1 < NT) stage(t + 1, cb ^ 1);
        compute(cb);
        __syncthreads();
    }

    if constexpr (OUTT) {
        short* Y = (short*)Yv;
        #pragma unroll
        for (int fm = 0; fm < 2; ++fm) {
            int mb = m0 + wm0 + fm * 16 + g * 4;
            if (mb < M) {
                float4 b4 = *(const float4*)&bias[mb];
                float4 s4 = *(const float4*)&scale[mb];
                float4 h4 = *(const float4*)&shift[mb];
                #pragma unroll
                for (int fn = 0; fn < 2; ++fn) {
                    int n = n0 + wn0 + fn * 16 + r;
                    f32x4 a = acc[fm][fn];
                    bf16x4 o;
                    o[0] = f2h(fmaxf(fmaf(a[0] + b4.x, s4.x, h4.x), 0.f));
                    o[1] = f2h(fmaxf(fmaf(a[1] + b4.y, s4.y, h4.y), 0.f));
                    o[2] = f2h(fmaxf(fmaf(a[2] + b4.z, s4.z, h4.z), 0.f));
                    o[3] = f2h(fmaxf(fmaf(a[3] + b4.w, s4.w, h4.w), 0.f));
                    *(bf16x4*)&Y[((size_t)b * N_PTS + n) * ostride + mb] = o;
                }
            }
        }
    } else {
        float* Y = (float*)Yv;
        #pragma unroll
        for (int fm = 0; fm < 2; ++fm) {
            int mbase = m0 + wm0 + fm * 16 + g * 4;
            #pragma unroll
            for (int e = 0; e < 4; ++e) {
                int mm = mbase + e;
                if (mm >= M) continue;
                float bs = bias[mm], sc = scale[mm], sh = shift[mm];
                #pragma unroll
                for (int fn = 0; fn < 2; ++fn) {
                    int n = n0 + wn0 + fn * 16 + r;
                    float v = fmaxf(fmaf(acc[fm][fn][e] + bs, sc, sh), 0.f);
                    Y[(size_t)b * ybs + (size_t)mm * N_PTS + n] = v;
                }
            }
        }
    }
}

// eigen finalize body (round-9 validated) ------------------------------------
__device__ __forceinline__ void finalize_body(
    const float* __restrict__ xyz, const float* __restrict__ pbuf,
    const float* __restrict__ ew1, const float* __restrict__ eb1,
    const float* __restrict__ ew2, const float* __restrict__ eb2,
    short* __restrict__ zinT, float* __restrict__ out, int bx, int tid)
{
    int id = bx * 256 + tid;
    if (id >= BATCH * N_PTS) return;
    int b = id >> 12, i = id & (N_PTS - 1);

    out[id*3+0] = xyz[id*3+0];
    out[id*3+1] = xyz[id*3+1];
    out[id*3+2] = xyz[id*3+2];

    double s[10] = {0,0,0,0,0,0,0,0,0,0};
    for (int js = 0; js < JS; ++js) {
        const float* src = pbuf + ((size_t)(b * JS + js) * N_PTS + i) * 16;
        #pragma unroll
        for (int q = 0; q < 10; ++q) s[q] += (double)src[q];
    }
    const float* xb = xyz + (size_t)b * N_PTS * 3;
    float xi = xb[i*3+0], yi = xb[i*3+1], zi = xb[i*3+2];
    s[0] -= 1.0;
    s[1] -= (double)(float)(_Float16)xi;
    s[2] -= (double)(float)(_Float16)yi;
    s[3] -= (double)(float)(_Float16)zi;
    s[4] -= (double)(float)(_Float16)(xi * xi);
    s[5] -= (double)(float)(_Float16)(xi * yi);
    s[6] -= (double)(float)(_Float16)(xi * zi);
    s[7] -= (double)(float)(_Float16)(yi * yi);
    s[8] -= (double)(float)(_Float16)(yi * zi);
    s[9] -= (double)(float)(_Float16)(zi * zi);

    double cnt = s[0];
    double denom = fmax(cnt, 1.0);
    double mx = s[1] / denom, my = s[2] / denom, mz = s[3] / denom;
    const double invN = 1.0 / (double)N_PTS;
    double c00 = (s[4] - cnt * mx * mx) * invN;
    double c01 = (s[5] - cnt * mx * my) * invN;
    double c02 = (s[6] - cnt * mx * mz) * invN;
    double c11 = (s[7] - cnt * my * my) * invN;
    double c12 = (s[8] - cnt * my * mz) * invN;
    double c22 = (s[9] - cnt * mz * mz) * invN;

    double qm = (c00 + c11 + c22) / 3.0;
    double p1 = c01*c01 + c02*c02 + c12*c12;
    double a0 = c00 - qm, a1 = c11 - qm, a2 = c22 - qm;
    double p2 = a0*a0 + a1*a1 + a2*a2 + 2.0*p1;
    double e_lo, e_mid, e_hi;
    if (p2 < 1e-32) {
        e_lo = e_mid = e_hi = qm;
    } else {
        double p = sqrt(p2 / 6.0);
        double inv = 1.0 / p;
        double b00 = a0*inv, b11 = a1*inv, b22 = a2*inv;
        double b01 = c01*inv, b02 = c02*inv, b12 = c12*inv;
        double detB = b00*(b11*b22 - b12*b12)
                    - b01*(b01*b22 - b12*b02)
                    + b02*(b01*b12 - b11*b02);
        double r = 0.5 * detB;
        r = fmin(1.0, fmax(-1.0, r));
        double phi = acos(r) / 3.0;
        double two_p = 2.0 * p;
        e_hi = qm + two_p * cos(phi);
        e_lo = qm + two_p * cos(phi + 2.0943951023931953);
        e_mid = 3.0 * qm - e_hi - e_lo;
    }
    float e0 = (float)e_lo, e1 = (float)e_mid, e2 = (float)e_hi;

    float t[4];
    #pragma unroll
    for (int o = 0; o < 4; ++o)
        t[o] = fmaxf(e0 * ew1[o*3+0] + e1 * ew1[o*3+1] +
                     e2 * ew1[o*3+2] + eb1[o], 0.f);
    bf16x4 ov;
    #pragma unroll
    for (int o = 0; o < 4; ++o) {
        float h = t[0]*ew2[o*4+0] + t[1]*ew2[o*4+1] +
                  t[2]*ew2[o*4+2] + t[3]*ew2[o*4+3] + eb2[o];
        ov[o] = f2h(h);
    }
    *(bf16x4*)&zinT[((size_t)b * N_PTS + i) * 192 + 160] = ov;
}

// DG2+DG3 fused body (round-16 validated) ------------------------------------
__device__ __forceinline__ void dg23_body(
    const short* __restrict__ W2b, const short* __restrict__ W3b,
    const short* __restrict__ XT,
    const float* __restrict__ cb2, const float* __restrict__ cs2,
    const float* __restrict__ ct2,
    const float* __restrict__ cb3, const float* __restrict__ cs3,
    const float* __restrict__ ct3,
    short* __restrict__ zinT, int x, int b, int tid, char* smem)
{
    constexpr int BK = 64;
    short (*Wl)[64][64] = (short(*)[64][64])smem;
    short (*Xl)[64][64] = (short(*)[64][64])(smem + 16384);
    short (*Wl3)[72] = (short(*)[72])(smem + 32768);
    short (*Xl3)[72] = (short(*)[72])(smem + 32768 + 9216);

    const int lane = tid & 63, wave = tid >> 6;
    const int g = lane >> 4, r = lane & 15;
    const int wr = wave >> 1, wc = wave & 1;
    const int wm0 = wr * 32, wn0 = wc * 32;
    const int n0 = x * 64;
    const int Kp = 256, NT = 4;

    const int lrow8 = lane >> 3;
    const int lchunk = lane & 7;

    #pragma unroll
    for (int u = 0; u < 2; ++u) {
        int id = u * 256 + tid;
        int m = id >> 3, c = id & 7;
        *(bf16x8*)&Wl3[m][c * 8] = *(const bf16x8*)&W3b[(size_t)m * 64 + c * 8];
    }

    f32x4 acc[2][2];
    #pragma unroll
    for (int i = 0; i < 2; ++i)
        #pragma unroll
        for (int j = 0; j < 2; ++j) acc[i][j] = (f32x4){0.f,0.f,0.f,0.f};

    auto stage = [&](int t, int nb) {
        #pragma unroll
        for (int i = 0; i < 2; ++i) {
            int row0 = wave * 16 + i * 8;
            int row = row0 + lrow8;
            int cl = lchunk ^ (row & 7);
            gload_lds16(&W2b[(size_t)row * Kp + t * BK + cl * 8],
                        &Wl[nb][row0][0]);
            gload_lds16(&XT[((size_t)b * N_PTS + n0 + row) * Kp + t * BK + cl * 8],
                        &Xl[nb][row0][0]);
        }
    };
    auto compute = [&](int cb) {
        #pragma unroll
        for (int q = 0; q < 2; ++q) {
            const int pc = ((q * 4 + g) ^ (r & 7)) * 8;
            #pragma unroll
            for (int fn = 0; fn < 2; ++fn) {
                bf16x8 bb = *(const bf16x8*)&Xl[cb][wn0 + fn * 16 + r][pc];
                #pragma unroll
                for (int fm = 0; fm < 2; ++fm) {
                    bf16x8 a = *(const bf16x8*)&Wl[cb][wm0 + fm * 16 + r][pc];
                    acc[fm][fn] = __builtin_amdgcn_mfma_f32_16x16x32_f16(
                        __builtin_bit_cast(f16x8, a),
                        __builtin_bit_cast(f16x8, bb),
                        acc[fm][fn], 0, 0, 0);
                }
            }
        }
    };

    stage(0, 0);
    __syncthreads();
    for (int t = 0; t < NT; ++t) {
        int cb = t & 1;
        if (t + 1 < NT) stage(t + 1, cb ^ 1);
        compute(cb);
        __syncthreads();
    }

    #pragma unroll
    for (int fm = 0; fm < 2; ++fm) {
        int mb = wm0 + fm * 16 + g * 4;
        float4 b4 = *(const float4*)&cb2[mb];
        float4 s4 = *(const float4*)&cs2[mb];
        float4 h4 = *(const float4*)&ct2[mb];
        #pragma unroll
        for (int fn = 0; fn < 2; ++fn) {
            int nl = wn0 + fn * 16 + r;
            f32x4 a = acc[fm][fn];
            bf16x4 o;
            o[0] = f2h(fmaxf(fmaf(a[0] + b4.x, s4.x, h4.x), 0.f));
            o[1] = f2h(fmaxf(fmaf(a[1] + b4.y, s4.y, h4.y), 0.f));
            o[2] = f2h(fmaxf(fmaf(a[2] + b4.z, s4.z, h4.z), 0.f));
            o[3] = f2h(fmaxf(fmaf(a[3] + b4.w, s4.w, h4.w), 0.f));
            *(bf16x4*)&Xl3[nl][mb] = o;
        }
    }
    __syncthreads();

    f32x4 acc3[2][2];
    #pragma unroll
    for (int i = 0; i < 2; ++i)
        #pragma unroll
        for (int j = 0; j < 2; ++j) acc3[i][j] = (f32x4){0.f,0.f,0.f,0.f};
    #pragma unroll
    for (int q = 0; q < 2; ++q) {
        #pragma unroll
        for (int fn = 0; fn < 2; ++fn) {
            bf16x8 bb = *(const bf16x8*)&Xl3[wn0 + fn * 16 + r][q * 32 + g * 8];
            #pragma unroll
            for (int fm = 0; fm < 2; ++fm) {
                bf16x8 a = *(const bf16x8*)&Wl3[wm0 + fm * 16 + r][q * 32 + g * 8];
                acc3[fm][fn] = __builtin_amdgcn_mfma_f32_16x16x32_f16(
                    __builtin_bit_cast(f16x8, a),
                    __builtin_bit_cast(f16x8, bb),
                    acc3[fm][fn], 0, 0, 0);
            }
        }
    }

    #pragma unroll
    for (int fm = 0; fm < 2; ++fm) {
        int mb = wm0 + fm * 16 + g * 4;
        if (mb < 32) {
            float4 b4 = *(const float4*)&cb3[mb];
            float4 s4 = *(const float4*)&cs3[mb];
            float4 h4 = *(const float4*)&ct3[mb];
            #pragma unroll
            for (int fn = 0; fn < 2; ++fn) {
                int n = n0 + wn0 + fn * 16 + r;
                f32x4 a = acc3[fm][fn];
                bf16x4 o;
                o[0] = f2h(fmaxf(fmaf(a[0] + b4.x, s4.x, h4.x), 0.f));
                o[1] = f2h(fmaxf(fmaf(a[1] + b4.y, s4.y, h4.y), 0.f));
                o[2] = f2h(fmaxf(fmaf(a[2] + b4.z, s4.z, h4.z), 0.f));
                o[3] = f2h(fmaxf(fmaf(a[3] + b4.w, s4.w, h4.w), 0.f));
                *(bf16x4*)&zinT[((size_t)b * N_PTS + n) * 192 + 128 + mb] = o;
            }
        }
    }
}

// ===========================================================================
// Mega-kernels
// ===========================================================================

// megaA: wconv || radius || transposes
__global__ __launch_bounds__(256) void megaA_kernel(
    WcArgs wa, int wcBlocks,
    const float* __restrict__ xyz, float* __restrict__ pmax,
    const float* __restrict__ h2, const float* __restrict__ h1,
    short* __restrict__ t_h2, short* __restrict__ zinT)
{
    __shared__ __align__(16) char smem[16896];
    const int tid = threadIdx.x;
    int bx = blockIdx.x;
    if (bx < wcBlocks) { wconv_body(wa, bx, tid); return; }
    bx -= wcBlocks;
    if (bx < 2048) {
        int ci = bx & 63, js = (bx >> 6) & 7, b = bx >> 9;
        radius_body(xyz, pmax, ci, js, b, tid, smem);
        return;
    }
    bx -= 2048;
    int x = bx & 127, rest = bx >> 7;
    int y = rest % 9, b = rest / 9;
    transpose_body(h2, h1, t_h2, zinT, x, y, b, tid, smem);
}

// megaB: eigen_accum || DG1
__global__ __launch_bounds__(256) void megaB_kernel(
    const float* __restrict__ xyz, const float* __restrict__ pmax,
    float* __restrict__ pbuf,
    const short* __restrict__ wb1, const short* __restrict__ t_h2,
    const float* __restrict__ db1, const float* __restrict__ ds1,
    const float* __restrict__ dt1, short* __restrict__ bufA)
{
    __shared__ __align__(16) char smem[32768];
    const int tid = threadIdx.x;
    int bx = blockIdx.x;
    if (bx < 2048) {
        int ci = bx & 63, js = (bx >> 6) & 7, b = bx >> 9;
        accum_body(xyz, pmax, pbuf, ci, js, b, tid, smem);
    } else {
        int e = bx - 2048;
        int x = e & 63, my = (e >> 6) & 3, b = e >> 8;
        gl_body<true>(wb1, t_h2, db1, ds1, dt1, bufA,
                      256, 1024, 256, 0, my * 64, x * 64, b, tid, smem);
    }
}

// megaC: finalize || dg23
__global__ __launch_bounds__(256) void megaC_kernel(
    const float* __restrict__ xyz, const float* __restrict__ pbuf,
    const float* __restrict__ ew1, const float* __restrict__ eb1,
    const float* __restrict__ ew2, const float* __restrict__ eb2,
    float* __restrict__ out,
    const short* __restrict__ wb2, const short* __restrict__ wb3,
    const short* __restrict__ bufA,
    const float* __restrict__ cb2, const float* __restrict__ cs2,
    const float* __restrict__ ct2,
    const float* __restrict__ cb3, const float* __restrict__ cs3,
    const float* __restrict__ ct3,
    short* __restrict__ zinT)
{
    __shared__ __align__(16) char smem[51200];
    const int tid = threadIdx.x;
    int bx = blockIdx.x;
    if (bx < 64) {
        finalize_body(xyz, pbuf, ew1, eb1, ew2, eb2, zinT, out, bx, tid);
    } else {
        int e = bx - 64;
        int x = e & 63, b = e >> 6;
        dg23_body(wb2, wb3, bufA, cb2, cs2, ct2, cb3, cs3, ct3,
                  zinT, x, b, tid, smem);
    }
}

// standalone gl GEMM (F1, F2, F3)
template<bool OUTT>
__global__ __launch_bounds__(256) void mfma_gemm_gl(
    const short* __restrict__ Wb, const short* __restrict__ XT,
    const float* __restrict__ bias, const float* __restrict__ scale,
    const float* __restrict__ shift, void* __restrict__ Yv,
    int M, int Kp, int ostride, size_t ybs)
{
    __shared__ __align__(16) char smem[32768];
    gl_body<OUTT>(Wb, XT, bias, scale, shift, Yv, M, Kp, ostride, ybs,
                  blockIdx.y * 64, blockIdx.x * 64, blockIdx.z,
                  threadIdx.x, smem);
}

// ---------------------------------------------------------------------------
extern "C" void kernel_launch(void* const* d_in, const int* in_sizes, int n_in,
                              void* d_out, int out_size, void* d_ws, size_t ws_size,
                              hipStream_t stream)
{
    const float* xyz   = (const float*)d_in[0];
    const float* h1    = (const float*)d_in[1];
    const float* h2_in = (const float*)d_in[2];
    const float* dg_w1 = (const float*)d_in[3];
    const float* dg_b1 = (const float*)d_in[4];
    const float* dg_s1 = (const float*)d_in[5];
    const float* dg_t1 = (const float*)d_in[6];
    const float* dg_w2 = (const float*)d_in[7];
    const float* dg_b2 = (const float*)d_in[8];
    const float* dg_s2 = (const float*)d_in[9];
    const float* dg_t2 = (const float*)d_in[10];
    const float* dg_w3 = (const float*)d_in[11];
    const float* dg_b3 = (const float*)d_in[12];
    const float* dg_s3 = (const float*)d_in[13];
    const float* dg_t3 = (const float*)d_in[14];
    const float* ed_w1 = (const float*)d_in[15];
    const float* ed_b1 = (const float*)d_in[16];
    const float* ed_w2 = (const float*)d_in[17];
    const float* ed_b2 = (const float*)d_in[18];
    const float* w1 = (const float*)d_in[19];
    const float* b1 = (const float*)d_in[20];
    const float* s1 = (const float*)d_in[21];
    const float* t1 = (const float*)d_in[22];
    const float* w2 = (const float*)d_in[23];
    const float* b2 = (const float*)d_in[24];
    const float* s2 = (const float*)d_in[25];
    const float* t2 = (const float*)d_in[26];
    const float* w3 = (const float*)d_in[27];
    const float* b3 = (const float*)d_in[28];
    const float* s3 = (const float*)d_in[29];
    const float* t3 = (const float*)d_in[30];

    float* out = (float*)d_out;

    char* ws = (char*)d_ws;
    size_t off = 0;
    auto alloc = [&](size_t bytes) {
        char* p = ws + off;
        off += (bytes + 255) & ~(size_t)255;
        return p;
    };
    float* pmax = (float*)alloc((size_t)BATCH * JS * 64 * 4);       // 8 KB
    short* wb1  = (short*)alloc((size_t)256 * 1024 * 2);
    short* wb2  = (short*)alloc((size_t)64  * 256  * 2);
    short* wb3  = (short*)alloc((size_t)64  * 64   * 2);
    short* wbf1 = (short*)alloc((size_t)512 * 192  * 2);
    short* wbf2 = (short*)alloc((size_t)256 * 512  * 2);
    short* wbf3 = (short*)alloc((size_t)128 * 256  * 2);
    short* zinT = (short*)alloc((size_t)BATCH * N_PTS * 192 * 2);   // 6.3 MB
    short* t_h2 = (short*)alloc((size_t)BATCH * N_PTS * 1024 * 2);  // 33.5 MB
    short* bufA = (short*)alloc((size_t)BATCH * N_PTS * 256 * 2);   // 8.4 MB
    float* pbuf = (float*)alloc((size_t)BATCH * JS * N_PTS * 16 * 4); // 8.4 MB
    short* bufB = t_h2;   // [B][N][512] fp16 (t_h2 dead after DG1)
    short* bufD = bufA;   // [B][N][256] fp16 (bufA dead after dg23)

    WcArgs wa;
    int wcTotal;
    {
        const float* Wp[6] = {dg_w1, dg_w2, dg_w3, w1, w2, w3};
        short* Op[6] = {wb1, wb2, wb3, wbf1, wbf2, wbf3};
        int Mv[6] = {256, 64, 32, 512, 256, 128};
        int Kv[6] = {1024, 256, 64, 164, 512, 256};
        int Mp[6] = {256, 64, 64, 512, 256, 128};
        int Kp[6] = {1024, 256, 64, 192, 512, 256};
        int acc0 = 0;
        for (int l = 0; l < 6; ++l) {
            wa.W[l] = Wp[l]; wa.O[l] = Op[l];
            wa.M[l] = Mv[l]; wa.K[l] = Kv[l]; wa.Kp[l] = Kp[l];
            wa.start[l] = acc0;
            acc0 += Mp[l] * Kp[l];
        }
        wa.start[6] = acc0;
        wcTotal = acc0;
    }
    const int wcBlocks = (wcTotal + 255) / 256;

    {
        int grid = wcBlocks + 2048 + 128 * 9 * BATCH;
        megaA_kernel<<<grid, 256, 0, stream>>>(
            wa, wcBlocks, xyz, pmax, h2_in, h1, t_h2, zinT);
    }
    megaB_kernel<<<2048 + 64 * 4 * BATCH, 256, 0, stream>>>(
        xyz, pmax, pbuf, wb1, t_h2, dg_b1, dg_s1, dg_t1, bufA);
    megaC_kernel<<<64 + 64 * BATCH, 256, 0, stream>>>(
        xyz, pbuf, ed_w1, ed_b1, ed_w2, ed_b2, out,
        wb2, wb3, bufA, dg_b2, dg_s2, dg_t2, dg_b3, dg_s3, dg_t3, zinT);

    mfma_gemm_gl<true><<<dim3(N_PTS/64, 8, BATCH), 256, 0, stream>>>(
        wbf1, zinT, b1, s1, t1, bufB, 512, 192, 512, 0);
    mfma_gemm_gl<true><<<dim3(N_PTS/64, 4, BATCH), 256, 0, stream>>>(
        wbf2, bufB, b2, s2, t2, bufD, 256, 512, 256, 0);
    mfma_gemm_gl<false><<<dim3(N_PTS/64, 2, BATCH), 256, 0, stream>>>(
        wbf3, bufD, b3, s3, t3, out + (size_t)BATCH * N_PTS * 3, 128, 256, 0,
        (size_t)128 * N_PTS);
}

// Round 22
// 100.317 us; speedup vs baseline: 1.0984x; 1.0037x over previous
//
#include <hip/hip_runtime.h>
#include <math.h>

#define N_PTS 4096
#define BATCH 4
#define JS 8                  // j-split factor
#define JCH (N_PTS / JS)      // 512 points per j-chunk

typedef short bf16x8 __attribute__((ext_vector_type(8)));
typedef short bf16x4 __attribute__((ext_vector_type(4)));
typedef float f32x4 __attribute__((ext_vector_type(4)));
typedef _Float16 f16x8 __attribute__((ext_vector_type(8)));

__device__ inline short f2h(float f) {
    _Float16 h = (_Float16)f;
    return __builtin_bit_cast(short, h);
}

__device__ inline void gload_lds16(const void* g, void* l) {
    __builtin_amdgcn_global_load_lds(
        (const __attribute__((address_space(1))) unsigned int*)g,
        (__attribute__((address_space(3))) unsigned int*)l, 16, 0, 0);
}

// ---------------------------------------------------------------------------
// Weight-conversion args (6 layers)
// ---------------------------------------------------------------------------
struct WcArgs {
    const float* W[6];
    short* O[6];
    int M[6], K[6], Kp[6];
    int start[7];
};

// ===========================================================================
// Device bodies (math identical to rounds 14-21 validated kernels)
// ===========================================================================

// wconv body -----------------------------------------------------------------
__device__ __forceinline__ void wconv_body(const WcArgs& a, int bx, int tid)
{
    int id = bx * 256 + tid;
    if (id >= a.start[6]) return;
    int l = 0;
    #pragma unroll
    for (int q = 1; q < 6; ++q) if (id >= a.start[q]) l = q;
    int local = id - a.start[l];
    int kp = a.Kp[l];
    int mrow = local / kp, k = local - mrow * kp;
    float v = (mrow < a.M[l] && k < a.K[l]) ? a.W[l][(size_t)mrow * a.K[l] + k] : 0.f;
    a.O[l][local] = f2h(v);
}

// radius body (triangular; per-block partial max, no atomics) ----------------
__device__ __forceinline__ void radius_body(
    const float* __restrict__ xyz, float* __restrict__ pmax,
    int ci, int js, int b, int tid, char* smem)
{
    if (ci >= 8 * js + 8) return;              // uniform triangular exit
    float4* sj = (float4*)smem;                // JCH*16 = 8 KB
    float* wred = (float*)(smem + JCH * 16);
    const float* xb = xyz + (size_t)b * N_PTS * 3;
    const int j0 = js * JCH;
    for (int idx = tid; idx < JCH; idx += 256) {
        int j = j0 + idx;
        float x = xb[j*3+0], y = xb[j*3+1], z = xb[j*3+2];
        sj[idx] = make_float4(x, y, z, fmaf(x, x, fmaf(y, y, z * z)));
    }
    __syncthreads();
    const int il = tid & 63;
    const int jq = tid >> 6;
    const int i = ci * 64 + il;
    const float xi = xb[i*3+0], yi = xb[i*3+1], zi = xb[i*3+2];
    const float x2i = fmaf(xi, xi, fmaf(yi, yi, zi * zi));
    float m = 0.f;
    const int jb = jq * (JCH / 4);
    #pragma unroll 4
    for (int j = jb; j < jb + JCH / 4; ++j) {
        float4 p = sj[j];
        float dot = fmaf(xi, p.x, fmaf(yi, p.y, zi * p.z));
        float d2 = fmaf(-2.f, dot, x2i + p.w);
        m = fmaxf(m, d2);
    }
    for (int off = 32; off >= 1; off >>= 1) m = fmaxf(m, __shfl_down(m, off));
    if ((tid & 63) == 0) wred[tid >> 6] = m;
    __syncthreads();
    if (tid == 0) {
        float mm = fmaxf(fmaxf(wred[0], wred[1]), fmaxf(wred[2], wred[3]));
        pmax[((size_t)b * JS + js) * 64 + ci] = mm;
    }
}

// transpose body (r22): ASYNC gload_lds load phase. LDS tile [128][32] f32,
// LINEAR dest (1KB per gload = 8 rows x 128B); global source quad
// pre-swizzled q = p ^ ((row>>3)&7)  (selector wave-iter-uniform).
// Involution identical to r19: element (c,n) sits at tile[c][n ^ 4*((c>>3)&7)],
// so the write phase is byte-for-byte the r19-validated code.
__device__ __forceinline__ void transpose_body(
    const float* __restrict__ h2, const float* __restrict__ h1,
    short* __restrict__ t_h2, short* __restrict__ zinT,
    int x, int y, int b, int tid, char* smem)
{
    float (*tile)[32] = (float(*)[32])smem;    // 16 KB
    const int n0 = x * 32;
    const float* src = (y < 8)
        ? h2 + ((size_t)b * 1024 + y * 128) * N_PTS
        : h1 + (size_t)b * 128 * N_PTS;
    const int wave = tid >> 6, lane = tid & 63;
    const int rl = lane >> 3, p = lane & 7;
    // async load: 4 gload per wave, fire-and-forget until the barrier
    #pragma unroll
    for (int i = 0; i < 4; ++i) {
        int row0 = wave * 32 + i * 8;          // wave-uniform LDS base row
        int row = row0 + rl;
        int q = p ^ ((wave * 4 + i) & 7);      // inverse-swizzled source quad
        gload_lds16(&src[(size_t)row * N_PTS + n0 + q * 4], &tile[row0][0]);
    }
    __syncthreads();                            // drains gload_lds
    // write: 32 n x 16 channel-groups(8) = 512, 2 iters (r19-validated)
    if (y < 8) {
        const int c0 = y * 128;
        #pragma unroll
        for (int it = 0; it < 2; ++it) {
            int idx = it * 256 + tid;
            int n = idx >> 4, cg = idx & 15;
            bf16x8 v;
            #pragma unroll
            for (int j = 0; j < 8; ++j) {
                int c = cg * 8 + j;
                v[j] = f2h(tile[c][n ^ (4 * ((c >> 3) & 7))]);
            }
            *(bf16x8*)&t_h2[((size_t)b * N_PTS + n0 + n) * 1024 + c0 + cg * 8] = v;
        }
    } else {
        #pragma unroll
        for (int it = 0; it < 2; ++it) {
            int idx = it * 256 + tid;
            int n = idx >> 4, cg = idx & 15;
            bf16x8 v;
            #pragma unroll
            for (int j = 0; j < 8; ++j) {
                int c = cg * 8 + j;
                v[j] = f2h(tile[c][n ^ (4 * ((c >> 3) & 7))]);
            }
            *(bf16x8*)&zinT[((size_t)b * N_PTS + n0 + n) * 192 + cg * 8] = v;
        }
        for (int idx = tid; idx < 32 * 7; idx += 256) {
            int n = idx / 7, cq = 164 + (idx % 7) * 4;
            bf16x4 z = {0, 0, 0, 0};
            *(bf16x4*)&zinT[((size_t)b * N_PTS + n0 + n) * 192 + cq] = z;
        }
    }
}

// eigen accumulate body (MFMA mask GEMM; r2 from exact pmax reduce) ----------
__device__ __forceinline__ void accum_body(
    const float* __restrict__ xyz, const float* __restrict__ pmax,
    float* __restrict__ pbuf, int ci, int js, int b, int tid, char* smem)
{
    float4* sj4 = (float4*)smem;                               // 8 KB
    _Float16 (*Ft)[JCH + 8] = (_Float16(*)[JCH + 8])(smem + 8192);  // 16.25 KB
    float* redbuf = (float*)(smem + 8192 + 16 * (JCH + 8) * 2);

    const int lane = tid & 63, wave = tid >> 6;

    float mval = 0.f;
    for (int e = tid; e < 512; e += 256) {
        int js2 = e >> 6, ci2 = e & 63;
        float v = (ci2 < 8 * js2 + 8) ? pmax[((size_t)b * JS + js2) * 64 + ci2] : 0.f;
        mval = fmaxf(mval, v);
    }
    for (int off = 32; off >= 1; off >>= 1) mval = fmaxf(mval, __shfl_down(mval, off));
    if (lane == 0) redbuf[wave] = mval;

    const float* xb = xyz + (size_t)b * N_PTS * 3;
    const int j0g = js * JCH;
    for (int idx = tid; idx < JCH; idx += 256) {
        int j = j0g + idx;
        float x = xb[j*3+0], y = xb[j*3+1], z = xb[j*3+2];
        sj4[idx] = make_float4(x, y, z, fmaf(x, x, fmaf(y, y, z * z)));
        Ft[0][idx] = (_Float16)1.f;
        Ft[1][idx] = (_Float16)x;
        Ft[2][idx] = (_Float16)y;
        Ft[3][idx] = (_Float16)z;
        Ft[4][idx] = (_Float16)(x * x);
        Ft[5][idx] = (_Float16)(x * y);
        Ft[6][idx] = (_Float16)(x * z);
        Ft[7][idx] = (_Float16)(y * y);
        Ft[8][idx] = (_Float16)(y * z);
        Ft[9][idx] = (_Float16)(z * z);
        Ft[10][idx] = (_Float16)0.f; Ft[11][idx] = (_Float16)0.f;
        Ft[12][idx] = (_Float16)0.f; Ft[13][idx] = (_Float16)0.f;
        Ft[14][idx] = (_Float16)0.f; Ft[15][idx] = (_Float16)0.f;
    }
    __syncthreads();
    const float mm = fmaxf(fmaxf(redbuf[0], redbuf[1]), fmaxf(redbuf[2], redbuf[3]));
    const float r2 = 0.01f * mm;

    const int r = lane & 15, g = lane >> 4;
    const int i_wf = ci * 64 + wave * 16 + r;
    const float xi = xb[i_wf*3+0], yi = xb[i_wf*3+1], zi = xb[i_wf*3+2];
    const float x2i = fmaf(xi, xi, fmaf(yi, yi, zi * zi));

    f32x4 acc = (f32x4){0.f, 0.f, 0.f, 0.f};
    #pragma unroll 4
    for (int t = 0; t < JCH / 32; ++t) {
        const int jb = t * 32 + g * 8;
        f16x8 wfv;
        #pragma unroll
        for (int s = 0; s < 8; ++s) {
            float4 p = sj4[jb + s];
            float dot = fmaf(xi, p.x, fmaf(yi, p.y, zi * p.z));
            float d2 = fmaf(-2.f, dot, x2i + p.w);
            wfv[s] = (d2 < r2) ? (_Float16)1.f : (_Float16)0.f;
        }
        f16x8 fv = *(const f16x8*)&Ft[r][jb];
        acc = __builtin_amdgcn_mfma_f32_16x16x32_f16(wfv, fv, acc, 0, 0, 0);
    }

    const int i_out = ci * 64 + wave * 16 + g * 4;
    float* dst = pbuf + ((size_t)(b * JS + js) * N_PTS + i_out) * 16 + r;
    #pragma unroll
    for (int e = 0; e < 4; ++e) dst[(size_t)e * 16] = acc[e];
}

// gl GEMM body (round-14/15 validated) ---------------------------------------
template<bool OUTT>
__device__ __forceinline__ void gl_body(
    const short* __restrict__ Wb, const short* __restrict__ XT,
    const float* __restrict__ bias, const float* __restrict__ scale,
    const float* __restrict__ shift, void* __restrict__ Yv,
    int M, int Kp, int ostride, size_t ybs,
    int m0, int n0, int b, int tid, char* smem)
{
    constexpr int BK = 64;
    short (*Wl)[64][BK] = (short(*)[64][BK])smem;              // 16 KB
    short (*Xl)[64][BK] = (short(*)[64][BK])(smem + 16384);    // 16 KB

    const int lane = tid & 63, wave = tid >> 6;
    const int g = lane >> 4, r = lane & 15;
    const int wr = wave >> 1, wc = wave & 1;
    const int wm0 = wr * 32, wn0 = wc * 32;
    const int NT = Kp / BK;

    const int lrow8 = lane >> 3;
    const int lchunk = lane & 7;

    f32x4 acc[2][2];
    #pragma unroll
    for (int i = 0; i < 2; ++i)
        #pragma unroll
        for (int j = 0; j < 2; ++j) acc[i][j] = (f32x4){0.f,0.f,0.f,0.f};

    auto stage = [&](int t, int nb) {
        #pragma unroll
        for (int i = 0; i < 2; ++i) {
            int row0 = wave * 16 + i * 8;
            int row = row0 + lrow8;
            int cl = lchunk ^ (row & 7);
            gload_lds16(&Wb[(size_t)(m0 + row) * Kp + t * BK + cl * 8],
                        &Wl[nb][row0][0]);
            gload_lds16(&XT[((size_t)b * N_PTS + n0 + row) * Kp + t * BK + cl * 8],
                        &Xl[nb][row0][0]);
        }
    };
    auto compute = [&](int cb) {
        #pragma unroll
        for (int q = 0; q < 2; ++q) {
            const int pc = ((q * 4 + g) ^ (r & 7)) * 8;
            #pragma unroll
            for (int fn = 0; fn < 2; ++fn) {
                bf16x8 bb = *(const bf16x8*)&Xl[cb][wn0 + fn * 16 + r][pc];
                #pragma unroll
                for (int fm = 0; fm < 2; ++fm) {
                    bf16x8 a = *(const bf16x8*)&Wl[cb][wm0 + fm * 16 + r][pc];
                    acc[fm][fn] = __builtin_amdgcn_mfma_f32_16x16x32_f16(
                        __builtin_bit_cast(f16x8, a),
                        __builtin_bit_cast(f16x8, bb),
                        acc[fm][fn], 0, 0, 0);
                }
            }
        }
    };

    stage(0, 0);
    __syncthreads();
    for (int t = 0; t < NT; ++t) {
        int cb = t & 1;
        if (t + 1 < NT) stage(t + 1, cb ^ 1);
        compute(cb);
        __syncthreads();
    }

    if constexpr (OUTT) {
        short* Y = (short*)Yv;
        #pragma unroll
        for (int fm = 0; fm < 2; ++fm) {
            int mb = m0 + wm0 + fm * 16 + g * 4;
            if (mb < M) {
                float4 b4 = *(const float4*)&bias[mb];
                float4 s4 = *(const float4*)&scale[mb];
                float4 h4 = *(const float4*)&shift[mb];
                #pragma unroll
                for (int fn = 0; fn < 2; ++fn) {
                    int n = n0 + wn0 + fn * 16 + r;
                    f32x4 a = acc[fm][fn];
                    bf16x4 o;
                    o[0] = f2h(fmaxf(fmaf(a[0] + b4.x, s4.x, h4.x), 0.f));
                    o[1] = f2h(fmaxf(fmaf(a[1] + b4.y, s4.y, h4.y), 0.f));
                    o[2] = f2h(fmaxf(fmaf(a[2] + b4.z, s4.z, h4.z), 0.f));
                    o[3] = f2h(fmaxf(fmaf(a[3] + b4.w, s4.w, h4.w), 0.f));
                    *(bf16x4*)&Y[((size_t)b * N_PTS + n) * ostride + mb] = o;
                }
            }
        }
    } else {
        float* Y = (float*)Yv;
        #pragma unroll
        for (int fm = 0; fm < 2; ++fm) {
            int mbase = m0 + wm0 + fm * 16 + g * 4;
            #pragma unroll
            for (int e = 0; e < 4; ++e) {
                int mm = mbase + e;
                if (mm >= M) continue;
                float bs = bias[mm], sc = scale[mm], sh = shift[mm];
                #pragma unroll
                for (int fn = 0; fn < 2; ++fn) {
                    int n = n0 + wn0 + fn * 16 + r;
                    float v = fmaxf(fmaf(acc[fm][fn][e] + bs, sc, sh), 0.f);
                    Y[(size_t)b * ybs + (size_t)mm * N_PTS + n] = v;
                }
            }
        }
    }
}

// eigen finalize body (round-9 validated) ------------------------------------
__device__ __forceinline__ void finalize_body(
    const float* __restrict__ xyz, const float* __restrict__ pbuf,
    const float* __restrict__ ew1, const float* __restrict__ eb1,
    const float* __restrict__ ew2, const float* __restrict__ eb2,
    short* __restrict__ zinT, float* __restrict__ out, int bx, int tid)
{
    int id = bx * 256 + tid;
    if (id >= BATCH * N_PTS) return;
    int b = id >> 12, i = id & (N_PTS - 1);

    out[id*3+0] = xyz[id*3+0];
    out[id*3+1] = xyz[id*3+1];
    out[id*3+2] = xyz[id*3+2];

    double s[10] = {0,0,0,0,0,0,0,0,0,0};
    for (int js = 0; js < JS; ++js) {
        const float* src = pbuf + ((size_t)(b * JS + js) * N_PTS + i) * 16;
        #pragma unroll
        for (int q = 0; q < 10; ++q) s[q] += (double)src[q];
    }
    const float* xb = xyz + (size_t)b * N_PTS * 3;
    float xi = xb[i*3+0], yi = xb[i*3+1], zi = xb[i*3+2];
    s[0] -= 1.0;
    s[1] -= (double)(float)(_Float16)xi;
    s[2] -= (double)(float)(_Float16)yi;
    s[3] -= (double)(float)(_Float16)zi;
    s[4] -= (double)(float)(_Float16)(xi * xi);
    s[5] -= (double)(float)(_Float16)(xi * yi);
    s[6] -= (double)(float)(_Float16)(xi * zi);
    s[7] -= (double)(float)(_Float16)(yi * yi);
    s[8] -= (double)(float)(_Float16)(yi * zi);
    s[9] -= (double)(float)(_Float16)(zi * zi);

    double cnt = s[0];
    double denom = fmax(cnt, 1.0);
    double mx = s[1] / denom, my = s[2] / denom, mz = s[3] / denom;
    const double invN = 1.0 / (double)N_PTS;
    double c00 = (s[4] - cnt * mx * mx) * invN;
    double c01 = (s[5] - cnt * mx * my) * invN;
    double c02 = (s[6] - cnt * mx * mz) * invN;
    double c11 = (s[7] - cnt * my * my) * invN;
    double c12 = (s[8] - cnt * my * mz) * invN;
    double c22 = (s[9] - cnt * mz * mz) * invN;

    double qm = (c00 + c11 + c22) / 3.0;
    double p1 = c01*c01 + c02*c02 + c12*c12;
    double a0 = c00 - qm, a1 = c11 - qm, a2 = c22 - qm;
    double p2 = a0*a0 + a1*a1 + a2*a2 + 2.0*p1;
    double e_lo, e_mid, e_hi;
    if (p2 < 1e-32) {
        e_lo = e_mid = e_hi = qm;
    } else {
        double p = sqrt(p2 / 6.0);
        double inv = 1.0 / p;
        double b00 = a0*inv, b11 = a1*inv, b22 = a2*inv;
        double b01 = c01*inv, b02 = c02*inv, b12 = c12*inv;
        double detB = b00*(b11*b22 - b12*b12)
                    - b01*(b01*b22 - b12*b02)
                    + b02*(b01*b12 - b11*b02);
        double r = 0.5 * detB;
        r = fmin(1.0, fmax(-1.0, r));
        double phi = acos(r) / 3.0;
        double two_p = 2.0 * p;
        e_hi = qm + two_p * cos(phi);
        e_lo = qm + two_p * cos(phi + 2.0943951023931953);
        e_mid = 3.0 * qm - e_hi - e_lo;
    }
    float e0 = (float)e_lo, e1 = (float)e_mid, e2 = (float)e_hi;

    float t[4];
    #pragma unroll
    for (int o = 0; o < 4; ++o)
        t[o] = fmaxf(e0 * ew1[o*3+0] + e1 * ew1[o*3+1] +
                     e2 * ew1[o*3+2] + eb1[o], 0.f);
    bf16x4 ov;
    #pragma unroll
    for (int o = 0; o < 4; ++o) {
        float h = t[0]*ew2[o*4+0] + t[1]*ew2[o*4+1] +
                  t[2]*ew2[o*4+2] + t[3]*ew2[o*4+3] + eb2[o];
        ov[o] = f2h(h);
    }
    *(bf16x4*)&zinT[((size_t)b * N_PTS + i) * 192 + 160] = ov;
}

// DG2+DG3 fused body (round-16 validated) ------------------------------------
__device__ __forceinline__ void dg23_body(
    const short* __restrict__ W2b, const short* __restrict__ W3b,
    const short* __restrict__ XT,
    const float* __restrict__ cb2, const float* __restrict__ cs2,
    const float* __restrict__ ct2,
    const float* __restrict__ cb3, const float* __restrict__ cs3,
    const float* __restrict__ ct3,
    short* __restrict__ zinT, int x, int b, int tid, char* smem)
{
    constexpr int BK = 64;
    short (*Wl)[64][64] = (short(*)[64][64])smem;
    short (*Xl)[64][64] = (short(*)[64][64])(smem + 16384);
    short (*Wl3)[72] = (short(*)[72])(smem + 32768);
    short (*Xl3)[72] = (short(*)[72])(smem + 32768 + 9216);

    const int lane = tid & 63, wave = tid >> 6;
    const int g = lane >> 4, r = lane & 15;
    const int wr = wave >> 1, wc = wave & 1;
    const int wm0 = wr * 32, wn0 = wc * 32;
    const int n0 = x * 64;
    const int Kp = 256, NT = 4;

    const int lrow8 = lane >> 3;
    const int lchunk = lane & 7;

    #pragma unroll
    for (int u = 0; u < 2; ++u) {
        int id = u * 256 + tid;
        int m = id >> 3, c = id & 7;
        *(bf16x8*)&Wl3[m][c * 8] = *(const bf16x8*)&W3b[(size_t)m * 64 + c * 8];
    }

    f32x4 acc[2][2];
    #pragma unroll
    for (int i = 0; i < 2; ++i)
        #pragma unroll
        for (int j = 0; j < 2; ++j) acc[i][j] = (f32x4){0.f,0.f,0.f,0.f};

    auto stage = [&](int t, int nb) {
        #pragma unroll
        for (int i = 0; i < 2; ++i) {
            int row0 = wave * 16 + i * 8;
            int row = row0 + lrow8;
            int cl = lchunk ^ (row & 7);
            gload_lds16(&W2b[(size_t)row * Kp + t * BK + cl * 8],
                        &Wl[nb][row0][0]);
            gload_lds16(&XT[((size_t)b * N_PTS + n0 + row) * Kp + t * BK + cl * 8],
                        &Xl[nb][row0][0]);
        }
    };
    auto compute = [&](int cb) {
        #pragma unroll
        for (int q = 0; q < 2; ++q) {
            const int pc = ((q * 4 + g) ^ (r & 7)) * 8;
            #pragma unroll
            for (int fn = 0; fn < 2; ++fn) {
                bf16x8 bb = *(const bf16x8*)&Xl[cb][wn0 + fn * 16 + r][pc];
                #pragma unroll
                for (int fm = 0; fm < 2; ++fm) {
                    bf16x8 a = *(const bf16x8*)&Wl[cb][wm0 + fm * 16 + r][pc];
                    acc[fm][fn] = __builtin_amdgcn_mfma_f32_16x16x32_f16(
                        __builtin_bit_cast(f16x8, a),
                        __builtin_bit_cast(f16x8, bb),
                        acc[fm][fn], 0, 0, 0);
                }
            }
        }
    };

    stage(0, 0);
    __syncthreads();
    for (int t = 0; t < NT; ++t) {
        int cb = t & 1;
        if (t + 1 < NT) stage(t + 1, cb ^ 1);
        compute(cb);
        __syncthreads();
    }

    #pragma unroll
    for (int fm = 0; fm < 2; ++fm) {
        int mb = wm0 + fm * 16 + g * 4;
        float4 b4 = *(const float4*)&cb2[mb];
        float4 s4 = *(const float4*)&cs2[mb];
        float4 h4 = *(const float4*)&ct2[mb];
        #pragma unroll
        for (int fn = 0; fn < 2; ++fn) {
            int nl = wn0 + fn * 16 + r;
            f32x4 a = acc[fm][fn];
            bf16x4 o;
            o[0] = f2h(fmaxf(fmaf(a[0] + b4.x, s4.x, h4.x), 0.f));
            o[1] = f2h(fmaxf(fmaf(a[1] + b4.y, s4.y, h4.y), 0.f));
            o[2] = f2h(fmaxf(fmaf(a[2] + b4.z, s4.z, h4.z), 0.f));
            o[3] = f2h(fmaxf(fmaf(a[3] + b4.w, s4.w, h4.w), 0.f));
            *(bf16x4*)&Xl3[nl][mb] = o;
        }
    }
    __syncthreads();

    f32x4 acc3[2][2];
    #pragma unroll
    for (int i = 0; i < 2; ++i)
        #pragma unroll
        for (int j = 0; j < 2; ++j) acc3[i][j] = (f32x4){0.f,0.f,0.f,0.f};
    #pragma unroll
    for (int q = 0; q < 2; ++q) {
        #pragma unroll
        for (int fn = 0; fn < 2; ++fn) {
            bf16x8 bb = *(const bf16x8*)&Xl3[wn0 + fn * 16 + r][q * 32 + g * 8];
            #pragma unroll
            for (int fm = 0; fm < 2; ++fm) {
                bf16x8 a = *(const bf16x8*)&Wl3[wm0 + fm * 16 + r][q * 32 + g * 8];
                acc3[fm][fn] = __builtin_amdgcn_mfma_f32_16x16x32_f16(
                    __builtin_bit_cast(f16x8, a),
                    __builtin_bit_cast(f16x8, bb),
                    acc3[fm][fn], 0, 0, 0);
            }
        }
    }

    #pragma unroll
    for (int fm = 0; fm < 2; ++fm) {
        int mb = wm0 + fm * 16 + g * 4;
        if (mb < 32) {
            float4 b4 = *(const float4*)&cb3[mb];
            float4 s4 = *(const float4*)&cs3[mb];
            float4 h4 = *(const float4*)&ct3[mb];
            #pragma unroll
            for (int fn = 0; fn < 2; ++fn) {
                int n = n0 + wn0 + fn * 16 + r;
                f32x4 a = acc3[fm][fn];
                bf16x4 o;
                o[0] = f2h(fmaxf(fmaf(a[0] + b4.x, s4.x, h4.x), 0.f));
                o[1] = f2h(fmaxf(fmaf(a[1] + b4.y, s4.y, h4.y), 0.f));
                o[2] = f2h(fmaxf(fmaf(a[2] + b4.z, s4.z, h4.z), 0.f));
                o[3] = f2h(fmaxf(fmaf(a[3] + b4.w, s4.w, h4.w), 0.f));
                *(bf16x4*)&zinT[((size_t)b * N_PTS + n) * 192 + 128 + mb] = o;
            }
        }
    }
}

// ===========================================================================
// Mega-kernels
// ===========================================================================

// megaA: wconv || radius || transposes
__global__ __launch_bounds__(256) void megaA_kernel(
    WcArgs wa, int wcBlocks,
    const float* __restrict__ xyz, float* __restrict__ pmax,
    const float* __restrict__ h2, const float* __restrict__ h1,
    short* __restrict__ t_h2, short* __restrict__ zinT)
{
    __shared__ __align__(16) char smem[16896];
    const int tid = threadIdx.x;
    int bx = blockIdx.x;
    if (bx < wcBlocks) { wconv_body(wa, bx, tid); return; }
    bx -= wcBlocks;
    if (bx < 2048) {
        int ci = bx & 63, js = (bx >> 6) & 7, b = bx >> 9;
        radius_body(xyz, pmax, ci, js, b, tid, smem);
        return;
    }
    bx -= 2048;
    int x = bx & 127, rest = bx >> 7;
    int y = rest % 9, b = rest / 9;
    transpose_body(h2, h1, t_h2, zinT, x, y, b, tid, smem);
}

// megaB: eigen_accum || DG1
__global__ __launch_bounds__(256) void megaB_kernel(
    const float* __restrict__ xyz, const float* __restrict__ pmax,
    float* __restrict__ pbuf,
    const short* __restrict__ wb1, const short* __restrict__ t_h2,
    const float* __restrict__ db1, const float* __restrict__ ds1,
    const float* __restrict__ dt1, short* __restrict__ bufA)
{
    __shared__ __align__(16) char smem[32768];
    const int tid = threadIdx.x;
    int bx = blockIdx.x;
    if (bx < 2048) {
        int ci = bx & 63, js = (bx >> 6) & 7, b = bx >> 9;
        accum_body(xyz, pmax, pbuf, ci, js, b, tid, smem);
    } else {
        int e = bx - 2048;
        int x = e & 63, my = (e >> 6) & 3, b = e >> 8;
        gl_body<true>(wb1, t_h2, db1, ds1, dt1, bufA,
                      256, 1024, 256, 0, my * 64, x * 64, b, tid, smem);
    }
}

// megaC: finalize || dg23
__global__ __launch_bounds__(256) void megaC_kernel(
    const float* __restrict__ xyz, const float* __restrict__ pbuf,
    const float* __restrict__ ew1, const float* __restrict__ eb1,
    const float* __restrict__ ew2, const float* __restrict__ eb2,
    float* __restrict__ out,
    const short* __restrict__ wb2, const short* __restrict__ wb3,
    const short* __restrict__ bufA,
    const float* __restrict__ cb2, const float* __restrict__ cs2,
    const float* __restrict__ ct2,
    const float* __restrict__ cb3, const float* __restrict__ cs3,
    const float* __restrict__ ct3,
    short* __restrict__ zinT)
{
    __shared__ __align__(16) char smem[51200];
    const int tid = threadIdx.x;
    int bx = blockIdx.x;
    if (bx < 64) {
        finalize_body(xyz, pbuf, ew1, eb1, ew2, eb2, zinT, out, bx, tid);
    } else {
        int e = bx - 64;
        int x = e & 63, b = e >> 6;
        dg23_body(wb2, wb3, bufA, cb2, cs2, ct2, cb3, cs3, ct3,
                  zinT, x, b, tid, smem);
    }
}

// standalone gl GEMM (F1, F2, F3)
template<bool OUTT>
__global__ __launch_bounds__(256) void mfma_gemm_gl(
    const short* __restrict__ Wb, const short* __restrict__ XT,
    const float* __restrict__ bias, const float* __restrict__ scale,
    const float* __restrict__ shift, void* __restrict__ Yv,
    int M, int Kp, int ostride, size_t ybs)
{
    __shared__ __align__(16) char smem[32768];
    gl_body<OUTT>(Wb, XT, bias, scale, shift, Yv, M, Kp, ostride, ybs,
                  blockIdx.y * 64, blockIdx.x * 64, blockIdx.z,
                  threadIdx.x, smem);
}

// ---------------------------------------------------------------------------
extern "C" void kernel_launch(void* const* d_in, const int* in_sizes, int n_in,
                              void* d_out, int out_size, void* d_ws, size_t ws_size,
                              hipStream_t stream)
{
    const float* xyz   = (const float*)d_in[0];
    const float* h1    = (const float*)d_in[1];
    const float* h2_in = (const float*)d_in[2];
    const float* dg_w1 = (const float*)d_in[3];
    const float* dg_b1 = (const float*)d_in[4];
    const float* dg_s1 = (const float*)d_in[5];
    const float* dg_t1 = (const float*)d_in[6];
    const float* dg_w2 = (const float*)d_in[7];
    const float* dg_b2 = (const float*)d_in[8];
    const float* dg_s2 = (const float*)d_in[9];
    const float* dg_t2 = (const float*)d_in[10];
    const float* dg_w3 = (const float*)d_in[11];
    const float* dg_b3 = (const float*)d_in[12];
    const float* dg_s3 = (const float*)d_in[13];
    const float* dg_t3 = (const float*)d_in[14];
    const float* ed_w1 = (const float*)d_in[15];
    const float* ed_b1 = (const float*)d_in[16];
    const float* ed_w2 = (const float*)d_in[17];
    const float* ed_b2 = (const float*)d_in[18];
    const float* w1 = (const float*)d_in[19];
    const float* b1 = (const float*)d_in[20];
    const float* s1 = (const float*)d_in[21];
    const float* t1 = (const float*)d_in[22];
    const float* w2 = (const float*)d_in[23];
    const float* b2 = (const float*)d_in[24];
    const float* s2 = (const float*)d_in[25];
    const float* t2 = (const float*)d_in[26];
    const float* w3 = (const float*)d_in[27];
    const float* b3 = (const float*)d_in[28];
    const float* s3 = (const float*)d_in[29];
    const float* t3 = (const float*)d_in[30];

    float* out = (float*)d_out;

    char* ws = (char*)d_ws;
    size_t off = 0;
    auto alloc = [&](size_t bytes) {
        char* p = ws + off;
        off += (bytes + 255) & ~(size_t)255;
        return p;
    };
    float* pmax = (float*)alloc((size_t)BATCH * JS * 64 * 4);       // 8 KB
    short* wb1  = (short*)alloc((size_t)256 * 1024 * 2);
    short* wb2  = (short*)alloc((size_t)64  * 256  * 2);
    short* wb3  = (short*)alloc((size_t)64  * 64   * 2);
    short* wbf1 = (short*)alloc((size_t)512 * 192  * 2);
    short* wbf2 = (short*)alloc((size_t)256 * 512  * 2);
    short* wbf3 = (short*)alloc((size_t)128 * 256  * 2);
    short* zinT = (short*)alloc((size_t)BATCH * N_PTS * 192 * 2);   // 6.3 MB
    short* t_h2 = (short*)alloc((size_t)BATCH * N_PTS * 1024 * 2);  // 33.5 MB
    short* bufA = (short*)alloc((size_t)BATCH * N_PTS * 256 * 2);   // 8.4 MB
    float* pbuf = (float*)alloc((size_t)BATCH * JS * N_PTS * 16 * 4); // 8.4 MB
    short* bufB = t_h2;   // [B][N][512] fp16 (t_h2 dead after DG1)
    short* bufD = bufA;   // [B][N][256] fp16 (bufA dead after dg23)

    WcArgs wa;
    int wcTotal;
    {
        const float* Wp[6] = {dg_w1, dg_w2, dg_w3, w1, w2, w3};
        short* Op[6] = {wb1, wb2, wb3, wbf1, wbf2, wbf3};
        int Mv[6] = {256, 64, 32, 512, 256, 128};
        int Kv[6] = {1024, 256, 64, 164, 512, 256};
        int Mp[6] = {256, 64, 64, 512, 256, 128};
        int Kp[6] = {1024, 256, 64, 192, 512, 256};
        int acc0 = 0;
        for (int l = 0; l < 6; ++l) {
            wa.W[l] = Wp[l]; wa.O[l] = Op[l];
            wa.M[l] = Mv[l]; wa.K[l] = Kv[l]; wa.Kp[l] = Kp[l];
            wa.start[l] = acc0;
            acc0 += Mp[l] * Kp[l];
        }
        wa.start[6] = acc0;
        wcTotal = acc0;
    }
    const int wcBlocks = (wcTotal + 255) / 256;

    {
        int grid = wcBlocks + 2048 + 128 * 9 * BATCH;
        megaA_kernel<<<grid, 256, 0, stream>>>(
            wa, wcBlocks, xyz, pmax, h2_in, h1, t_h2, zinT);
    }
    megaB_kernel<<<2048 + 64 * 4 * BATCH, 256, 0, stream>>>(
        xyz, pmax, pbuf, wb1, t_h2, dg_b1, dg_s1, dg_t1, bufA);
    megaC_kernel<<<64 + 64 * BATCH, 256, 0, stream>>>(
        xyz, pbuf, ed_w1, ed_b1, ed_w2, ed_b2, out,
        wb2, wb3, bufA, dg_b2, dg_s2, dg_t2, dg_b3, dg_s3, dg_t3, zinT);

    mfma_gemm_gl<true><<<dim3(N_PTS/64, 8, BATCH), 256, 0, stream>>>(
        wbf1, zinT, b1, s1, t1, bufB, 512, 192, 512, 0);
    mfma_gemm_gl<true><<<dim3(N_PTS/64, 4, BATCH), 256, 0, stream>>>(
        wbf2, bufB, b2, s2, t2, bufD, 256, 512, 256, 0);
    mfma_gemm_gl<false><<<dim3(N_PTS/64, 2, BATCH), 256, 0, stream>>>(
        wbf3, bufD, b3, s3, t3, out + (size_t)BATCH * N_PTS * 3, 128, 256, 0,
        (size_t)128 * N_PTS);
}